// Round 1
// baseline (974.461 us; speedup 1.0000x reference)
//
#include <hip/hip_runtime.h>
#include <math.h>

#define HEADS 4
#define HD    64
#define CCH   256
#define NB    4
#define HH    48
#define WW    48
#define NN    (HH*WW)      // 2304
#define EPSBN 1e-5f

// ---------------------------------------------------------------------------
// 1x1 conv + folded BN:  Y[b][o][n] = (sum_c W[o][c] X[b][c][n]) * s_o + bias_o
// Tiled fp32 GEMM, 64x64 tile, 256 threads, 4x4 micro-tile per thread.
// ---------------------------------------------------------------------------
__global__ __launch_bounds__(256)
void conv1x1_bn_kernel(const float* __restrict__ X,   // [B][C][N]
                       const float* __restrict__ W,   // [C][C]
                       const float* __restrict__ gg, const float* __restrict__ bb,
                       const float* __restrict__ mm, const float* __restrict__ vv,
                       float* __restrict__ Y)         // [B][C][N]
{
    __shared__ float Wt[16][65];   // Wt[cc][o]
    __shared__ float Xt[16][64];   // Xt[cc][n]
    const int nt  = blockIdx.x;    // 0..35
    const int ot  = blockIdx.y;    // 0..3
    const int b   = blockIdx.z;    // 0..3
    const int tid = threadIdx.x;
    const int to  = tid >> 4;      // 0..15
    const int tn  = tid & 15;      // 0..15
    const int n0  = nt * 64, o0 = ot * 64;
    const float* Xb = X + (size_t)b * CCH * NN;

    float acc[4][4];
#pragma unroll
    for (int i = 0; i < 4; ++i)
#pragma unroll
        for (int j = 0; j < 4; ++j) acc[i][j] = 0.f;

    for (int k0 = 0; k0 < CCH; k0 += 16) {
        {
            int idx = tid;
#pragma unroll
            for (int it = 0; it < 4; ++it, idx += 256) {
                int cc = idx & 15, o = idx >> 4;
                Wt[cc][o] = W[(size_t)(o0 + o) * CCH + k0 + cc];
            }
        }
        {
            int idx = tid;
#pragma unroll
            for (int it = 0; it < 4; ++it, idx += 256) {
                int n = idx & 63, cc = idx >> 6;
                Xt[cc][n] = Xb[(size_t)(k0 + cc) * NN + n0 + n];
            }
        }
        __syncthreads();
#pragma unroll
        for (int cc = 0; cc < 16; ++cc) {
            float a0 = Wt[cc][to],      a1 = Wt[cc][16 + to];
            float a2 = Wt[cc][32 + to], a3 = Wt[cc][48 + to];
            float x0 = Xt[cc][tn],      x1 = Xt[cc][16 + tn];
            float x2 = Xt[cc][32 + tn], x3 = Xt[cc][48 + tn];
            acc[0][0] += a0*x0; acc[0][1] += a0*x1; acc[0][2] += a0*x2; acc[0][3] += a0*x3;
            acc[1][0] += a1*x0; acc[1][1] += a1*x1; acc[1][2] += a1*x2; acc[1][3] += a1*x3;
            acc[2][0] += a2*x0; acc[2][1] += a2*x1; acc[2][2] += a2*x2; acc[2][3] += a2*x3;
            acc[3][0] += a3*x0; acc[3][1] += a3*x1; acc[3][2] += a3*x2; acc[3][3] += a3*x3;
        }
        __syncthreads();
    }

#pragma unroll
    for (int i = 0; i < 4; ++i) {
        int o = o0 + i * 16 + to;
        float s    = gg[o] * rsqrtf(vv[o] + EPSBN);
        float bias = bb[o] - mm[o] * s;
        float* Yo = Y + ((size_t)b * CCH + o) * NN;
#pragma unroll
        for (int j = 0; j < 4; ++j) {
            int n = n0 + j * 16 + tn;
            Yo[n] = acc[i][j] * s + bias;
        }
    }
}

// ---------------------------------------------------------------------------
// Flash-style fp32 attention. One block = one (b,h) x 64 q-rows.
// Bc = 32 kv rows per tile. 4 threads per q-row, each owns 16 d-values.
// ---------------------------------------------------------------------------
__global__ __launch_bounds__(256)
void attn_kernel(const float* __restrict__ Qf,  // [B][C][N]
                 const float* __restrict__ Kf,
                 const float* __restrict__ Vf,
                 float* __restrict__ Yw)         // [B][C][N]
{
    __shared__ float Qs[64][68];
    __shared__ float Ks[32][68];
    __shared__ float Vs[32][68];
    __shared__ float Ps[64][36];

    const int qt  = blockIdx.x;    // 0..35
    const int bh  = blockIdx.y;    // 0..15
    const int b   = bh >> 2, h = bh & 3;
    const size_t base = ((size_t)b * CCH + h * HD) * NN;
    const float* Qh = Qf + base;
    const float* Kh = Kf + base;
    const float* Vh = Vf + base;

    const int tid = threadIdx.x;
    const int r   = tid >> 2;      // q row within tile, 0..63
    const int i   = tid & 3;       // 0..3
    const int n0  = qt * 64;

    // load Q tile (transpose: global [d][n] -> LDS [n][d])
    for (int idx = tid; idx < 64 * 64; idx += 256) {
        int n = idx & 63, d = idx >> 6;
        Qs[n][d] = Qh[(size_t)d * NN + n0 + n];
    }

    float yacc[16];
#pragma unroll
    for (int u = 0; u < 16; ++u) yacc[u] = 0.f;
    float mrow = -1e30f, lrow = 0.f;
    const float scale = 0.125f;   // 1/sqrt(64)
    const int d0 = i * 16;

    for (int k0 = 0; k0 < NN; k0 += 32) {
        __syncthreads();   // protect Ks/Vs (prev PV) and Qs (first iter)
        for (int idx = tid; idx < 32 * 64; idx += 256) {
            int n = idx & 31, d = idx >> 5;
            Ks[n][d] = Kh[(size_t)d * NN + k0 + n];
            Vs[n][d] = Vh[(size_t)d * NN + k0 + n];
        }
        __syncthreads();

        // scores: this thread computes kv columns i*8 .. i*8+7 of row r
        float s[8];
#pragma unroll
        for (int jj = 0; jj < 8; ++jj) s[jj] = 0.f;
#pragma unroll
        for (int d4 = 0; d4 < 16; ++d4) {
            float4 qv = *(const float4*)&Qs[r][d4 * 4];
#pragma unroll
            for (int jj = 0; jj < 8; ++jj) {
                float4 kv = *(const float4*)&Ks[i * 8 + jj][d4 * 4];
                s[jj] += qv.x * kv.x + qv.y * kv.y + qv.z * kv.z + qv.w * kv.w;
            }
        }
        float tmax = -1e30f;
#pragma unroll
        for (int jj = 0; jj < 8; ++jj) { s[jj] *= scale; tmax = fmaxf(tmax, s[jj]); }
        tmax = fmaxf(tmax, __shfl_xor(tmax, 1));
        tmax = fmaxf(tmax, __shfl_xor(tmax, 2));
        float mnew  = fmaxf(mrow, tmax);
        float alpha = __expf(mrow - mnew);
        float psum = 0.f;
#pragma unroll
        for (int jj = 0; jj < 8; ++jj) { s[jj] = __expf(s[jj] - mnew); psum += s[jj]; }
        psum += __shfl_xor(psum, 1);
        psum += __shfl_xor(psum, 2);
        lrow = lrow * alpha + psum;
        mrow = mnew;
#pragma unroll
        for (int jj = 0; jj < 8; ++jj) Ps[r][i * 8 + jj] = s[jj];
        __syncthreads();

        // PV: y[d] = y[d]*alpha + sum_k p[k] * V[k][d]
#pragma unroll
        for (int u = 0; u < 16; ++u) yacc[u] *= alpha;
#pragma unroll 8
        for (int kk = 0; kk < 32; ++kk) {
            float p = Ps[r][kk];
#pragma unroll
            for (int u = 0; u < 16; u += 4) {
                float4 v4 = *(const float4*)&Vs[kk][d0 + u];
                yacc[u]     += p * v4.x;
                yacc[u + 1] += p * v4.y;
                yacc[u + 2] += p * v4.z;
                yacc[u + 3] += p * v4.w;
            }
        }
    }

    // epilogue: normalize, stage through LDS, write transposed (coalesced)
    float inv = 1.f / lrow;
    __syncthreads();
#pragma unroll
    for (int u = 0; u < 16; ++u) Qs[r][d0 + u] = yacc[u] * inv;
    __syncthreads();
    float* Ywh = Yw + base;
    for (int idx = tid; idx < 64 * 64; idx += 256) {
        int n = idx & 63, d = idx >> 6;
        Ywh[(size_t)d * NN + n0 + n] = Qs[n][d];
    }
}

// ---------------------------------------------------------------------------
// depthwise 3x3 conv + BN on qf, accumulated into Yw:  Yw += pe(qf)
// ---------------------------------------------------------------------------
__global__ __launch_bounds__(256)
void pe_add_kernel(const float* __restrict__ Qf,   // [B][C][N]
                   const float* __restrict__ Wpe,  // [C][1][3][3]
                   const float* __restrict__ gg, const float* __restrict__ bb,
                   const float* __restrict__ mm, const float* __restrict__ vv,
                   float* __restrict__ Yw)
{
    int idx = blockIdx.x * 256 + threadIdx.x;   // [B][C][N] linear
    if (idx >= NB * CCH * NN) return;
    int n = idx % NN;
    int x = n % WW, y = n / WW;
    int c = (idx / NN) % CCH;
    const float* src = Qf + (size_t)(idx - n);  // base of this [b][c] plane

    float s    = gg[c] * rsqrtf(vv[c] + EPSBN);
    float bias = bb[c] - mm[c] * s;
    float accv = 0.f;
#pragma unroll
    for (int dy = -1; dy <= 1; ++dy) {
        int yy = y + dy;
        if (yy < 0 || yy >= HH) continue;
#pragma unroll
        for (int dx = -1; dx <= 1; ++dx) {
            int xx = x + dx;
            if (xx < 0 || xx >= WW) continue;
            accv += Wpe[c * 9 + (dy + 1) * 3 + (dx + 1)] * src[yy * WW + xx];
        }
    }
    Yw[idx] += accv * s + bias;
}

// ---------------------------------------------------------------------------
extern "C" void kernel_launch(void* const* d_in, const int* in_sizes, int n_in,
                              void* d_out, int out_size, void* d_ws, size_t ws_size,
                              hipStream_t stream) {
    const float* q      = (const float*)d_in[0];
    const float* k      = (const float*)d_in[1];
    const float* v      = (const float*)d_in[2];
    const float* wq_w   = (const float*)d_in[3];
    const float* wk_w   = (const float*)d_in[4];
    const float* wv_w   = (const float*)d_in[5];
    const float* proj_w = (const float*)d_in[6];
    const float* pe_w   = (const float*)d_in[7];
    const float* wq_g = (const float*)d_in[8],  *wq_b = (const float*)d_in[9];
    const float* wq_m = (const float*)d_in[10], *wq_v = (const float*)d_in[11];
    const float* wk_g = (const float*)d_in[12], *wk_b = (const float*)d_in[13];
    const float* wk_m = (const float*)d_in[14], *wk_v = (const float*)d_in[15];
    const float* wv_g = (const float*)d_in[16], *wv_b = (const float*)d_in[17];
    const float* wv_m = (const float*)d_in[18], *wv_v = (const float*)d_in[19];
    const float* pe_g = (const float*)d_in[20], *pe_b = (const float*)d_in[21];
    const float* pe_m = (const float*)d_in[22], *pe_v = (const float*)d_in[23];
    const float* pj_g = (const float*)d_in[24], *pj_b = (const float*)d_in[25];
    const float* pj_m = (const float*)d_in[26], *pj_v = (const float*)d_in[27];

    const size_t BCN = (size_t)NB * CCH * NN;   // 2,359,296 elements
    float* qf = (float*)d_ws;
    float* kf = qf + BCN;
    float* vf = kf + BCN;
    float* yw = vf + BCN;

    dim3 gConv(NN / 64, CCH / 64, NB);   // 36 x 4 x 4
    conv1x1_bn_kernel<<<gConv, 256, 0, stream>>>(q, wq_w, wq_g, wq_b, wq_m, wq_v, qf);
    conv1x1_bn_kernel<<<gConv, 256, 0, stream>>>(k, wk_w, wk_g, wk_b, wk_m, wk_v, kf);
    conv1x1_bn_kernel<<<gConv, 256, 0, stream>>>(v, wv_w, wv_g, wv_b, wv_m, wv_v, vf);

    dim3 gAttn(NN / 64, NB * HEADS);     // 36 x 16
    attn_kernel<<<gAttn, 256, 0, stream>>>(qf, kf, vf, yw);

    int total = NB * CCH * NN;
    pe_add_kernel<<<total / 256, 256, 0, stream>>>(qf, pe_w, pe_g, pe_b, pe_m, pe_v, yw);

    conv1x1_bn_kernel<<<gConv, 256, 0, stream>>>(yw, proj_w, pj_g, pj_b, pj_m, pj_v,
                                                 (float*)d_out);
}

// Round 2
// 299.299 us; speedup vs baseline: 3.2558x; 3.2558x over previous
//
#include <hip/hip_runtime.h>
#include <math.h>

#define HEADS 4
#define HD    64
#define CCH   256
#define NB    4
#define HH    48
#define WW    48
#define NN    (HH*WW)      // 2304
#define EPSBN 1e-5f

typedef unsigned short ushort_t;
typedef __attribute__((ext_vector_type(8))) short bfrag;   // 8 bf16 = 4 VGPR
typedef __attribute__((ext_vector_type(4))) float f32x4;   // MFMA C/D

static __device__ __forceinline__ ushort_t f2bf(float x) {
    unsigned int u = __float_as_uint(x);
    unsigned int r = (u + 0x7fffu + ((u >> 16) & 1u)) >> 16;   // RNE
    return (ushort_t)r;
}

// ---------------------------------------------------------------------------
// 1x1 conv + folded BN, fp32 compute.
// MODE 0: fp32 [b][c][n] out (proj)
// MODE 1: fp32 [b][c][n] out + bf16 [b][h][n][d] out scaled by 0.125 (q)
// MODE 2: bf16 [b][h][n][d] out (k)
// MODE 3: bf16 [b][c][n] out (v)
// ---------------------------------------------------------------------------
template<int MODE>
__global__ __launch_bounds__(256)
void conv1x1_bn_kernel(const float* __restrict__ X,   // [B][C][N]
                       const float* __restrict__ W,   // [C][C]
                       const float* __restrict__ gg, const float* __restrict__ bb,
                       const float* __restrict__ mm, const float* __restrict__ vv,
                       float* __restrict__ Ycn,       // fp32 [b][c][n] (MODE 0/1)
                       ushort_t* __restrict__ Ynd)    // bf16 out (MODE 1/2/3)
{
    __shared__ float Wt[16][65];
    __shared__ float Xt[16][64];
    __shared__ ushort_t Ot[64][72];    // bf16 [n][d] staging (MODE 1/2)

    const int nt  = blockIdx.x;
    const int ot  = blockIdx.y;
    const int b   = blockIdx.z;
    const int tid = threadIdx.x;
    const int to  = tid >> 4;
    const int tn  = tid & 15;
    const int n0  = nt * 64, o0 = ot * 64;
    const float* Xb = X + (size_t)b * CCH * NN;

    float acc[4][4];
#pragma unroll
    for (int i = 0; i < 4; ++i)
#pragma unroll
        for (int j = 0; j < 4; ++j) acc[i][j] = 0.f;

    for (int k0 = 0; k0 < CCH; k0 += 16) {
        {
            int idx = tid;
#pragma unroll
            for (int it = 0; it < 4; ++it, idx += 256) {
                int cc = idx & 15, o = idx >> 4;
                Wt[cc][o] = W[(size_t)(o0 + o) * CCH + k0 + cc];
            }
        }
        {
            int idx = tid;
#pragma unroll
            for (int it = 0; it < 4; ++it, idx += 256) {
                int n = idx & 63, cc = idx >> 6;
                Xt[cc][n] = Xb[(size_t)(k0 + cc) * NN + n0 + n];
            }
        }
        __syncthreads();
#pragma unroll
        for (int cc = 0; cc < 16; ++cc) {
            float a0 = Wt[cc][to],      a1 = Wt[cc][16 + to];
            float a2 = Wt[cc][32 + to], a3 = Wt[cc][48 + to];
            float x0 = Xt[cc][tn],      x1 = Xt[cc][16 + tn];
            float x2 = Xt[cc][32 + tn], x3 = Xt[cc][48 + tn];
            acc[0][0] += a0*x0; acc[0][1] += a0*x1; acc[0][2] += a0*x2; acc[0][3] += a0*x3;
            acc[1][0] += a1*x0; acc[1][1] += a1*x1; acc[1][2] += a1*x2; acc[1][3] += a1*x3;
            acc[2][0] += a2*x0; acc[2][1] += a2*x1; acc[2][2] += a2*x2; acc[2][3] += a2*x3;
            acc[3][0] += a3*x0; acc[3][1] += a3*x1; acc[3][2] += a3*x2; acc[3][3] += a3*x3;
        }
        __syncthreads();
    }

#pragma unroll
    for (int i = 0; i < 4; ++i) {
        int o = o0 + i * 16 + to;
        float s    = gg[o] * rsqrtf(vv[o] + EPSBN);
        float bias = bb[o] - mm[o] * s;
#pragma unroll
        for (int j = 0; j < 4; ++j) {
            int n = n0 + j * 16 + tn;
            float val = acc[i][j] * s + bias;
            if (MODE == 0 || MODE == 1)
                Ycn[((size_t)b * CCH + o) * NN + n] = val;
            if (MODE == 3)
                Ynd[((size_t)b * CCH + o) * NN + n] = f2bf(val);
            if (MODE == 1 || MODE == 2) {
                float v2 = (MODE == 1) ? val * 0.125f : val;
                Ot[j * 16 + tn][i * 16 + to] = f2bf(v2);
            }
        }
    }
    if (MODE == 1 || MODE == 2) {
        __syncthreads();
        // write bf16 [b][h][n][d], h == ot (64-channel head == 64-o tile)
        for (int idx = tid; idx < 512; idx += 256) {
            int r = idx >> 3, seg = idx & 7;
            *(uint4*)&Ynd[(((size_t)b * HEADS + ot) * NN + n0 + r) * HD + seg * 8] =
                *(const uint4*)&Ot[r][seg * 8];
        }
    }
}

// ---------------------------------------------------------------------------
// MFMA flash attention, bf16 inputs, fp32 softmax/accum.
// Block = (q-tile of 64 rows) x (b,h). 4 waves, wave = 16 q-rows.
// Bc = 32 kv per tile. Q/K in [n][d] bf16 (q pre-scaled), V in [d][n] bf16.
// ---------------------------------------------------------------------------
__global__ __launch_bounds__(256)
void attn_mfma_kernel(const ushort_t* __restrict__ Qnd,
                      const ushort_t* __restrict__ Knd,
                      const ushort_t* __restrict__ Vcn,
                      float* __restrict__ Yw)          // fp32 [b][c][n]
{
    __shared__ __align__(16) char smem[24064];
    ushort_t (*Qs)[72] = (ushort_t(*)[72])(smem);            // [64][72]
    ushort_t (*Ks)[72] = (ushort_t(*)[72])(smem + 9216);     // [32][72]
    ushort_t (*Vs)[40] = (ushort_t(*)[40])(smem + 13824);    // [64][40]  rows=d
    float    (*Os)[65] = (float(*)[65])(smem);               // epilogue overlay

    const int qt  = blockIdx.x;            // 0..35
    const int bh  = blockIdx.y;            // 0..15
    const int b   = bh >> 2, h = bh & 3;
    const int tid = threadIdx.x;
    const int lane = tid & 63, wv = tid >> 6;
    const int lr  = lane & 15;             // frag row/col index
    const int lg  = lane >> 4;             // k-group 0..3
    const int n0  = qt * 64;

    ushort_t (*Psw)[40] = (ushort_t(*)[40])(smem + 18944 + wv * 1280); // [16][40]

    const size_t ndbase = (size_t)(b * HEADS + h) * NN * HD;
    const size_t cnbase = ((size_t)b * CCH + h * HD) * NN;

    // stage Q tile -> Qs[64][72]
    for (int idx = tid; idx < 512; idx += 256) {
        int r = idx >> 3, seg = idx & 7;
        *(uint4*)&Qs[r][seg * 8] = *(const uint4*)&Qnd[ndbase + (size_t)(n0 + r) * HD + seg * 8];
    }
    __syncthreads();

    // Q A-fragments (invariant over kv loop): rows wv*16+lr, k=d
    bfrag qa0 = *(const bfrag*)&Qs[wv * 16 + lr][0  + lg * 8];
    bfrag qa1 = *(const bfrag*)&Qs[wv * 16 + lr][32 + lg * 8];

    f32x4 o0 = {0,0,0,0}, o1 = {0,0,0,0}, o2 = {0,0,0,0}, o3 = {0,0,0,0};
    float m[4] = {-1e30f, -1e30f, -1e30f, -1e30f};
    float l[4] = {0.f, 0.f, 0.f, 0.f};

    for (int k0 = 0; k0 < NN; k0 += 32) {
        __syncthreads();   // previous tile's reads of Ks/Vs complete
        {   // stage K (32x64) and V (64x32) -- one uint4 each per thread
            int r = tid >> 3, seg = tid & 7;
            *(uint4*)&Ks[r][seg * 8] =
                *(const uint4*)&Knd[ndbase + (size_t)(k0 + r) * HD + seg * 8];
            int d = tid >> 2, sg = tid & 3;
            *(uint4*)&Vs[d][sg * 8] =
                *(const uint4*)&Vcn[cnbase + (size_t)d * NN + k0 + sg * 8];
        }
        __syncthreads();

        // QK^T: S[16 q][32 k], two 16x16 col-tiles
        bfrag kb00 = *(const bfrag*)&Ks[lr][0  + lg * 8];
        bfrag kb01 = *(const bfrag*)&Ks[lr][32 + lg * 8];
        bfrag kb10 = *(const bfrag*)&Ks[16 + lr][0  + lg * 8];
        bfrag kb11 = *(const bfrag*)&Ks[16 + lr][32 + lg * 8];
        f32x4 s0 = {0,0,0,0}, s1 = {0,0,0,0};
        s0 = __builtin_amdgcn_mfma_f32_16x16x32_bf16(qa0, kb00, s0, 0, 0, 0);
        s0 = __builtin_amdgcn_mfma_f32_16x16x32_bf16(qa1, kb01, s0, 0, 0, 0);
        s1 = __builtin_amdgcn_mfma_f32_16x16x32_bf16(qa0, kb10, s1, 0, 0, 0);
        s1 = __builtin_amdgcn_mfma_f32_16x16x32_bf16(qa1, kb11, s1, 0, 0, 0);

        // online softmax. lane holds rows lg*4+rg (via regs), cols lr / 16+lr.
        float al[4];
#pragma unroll
        for (int rg = 0; rg < 4; ++rg) {
            float mx = fmaxf(s0[rg], s1[rg]);
            mx = fmaxf(mx, __shfl_xor(mx, 1));
            mx = fmaxf(mx, __shfl_xor(mx, 2));
            mx = fmaxf(mx, __shfl_xor(mx, 4));
            mx = fmaxf(mx, __shfl_xor(mx, 8));
            float mn = fmaxf(m[rg], mx);
            al[rg] = __expf(m[rg] - mn);
            m[rg] = mn;
            float p0 = __expf(s0[rg] - mn);
            float p1 = __expf(s1[rg] - mn);
            float ps = p0 + p1;
            ps += __shfl_xor(ps, 1);
            ps += __shfl_xor(ps, 2);
            ps += __shfl_xor(ps, 4);
            ps += __shfl_xor(ps, 8);
            l[rg] = l[rg] * al[rg] + ps;
            int row = lg * 4 + rg;
            Psw[row][lr]      = f2bf(p0);
            Psw[row][16 + lr] = f2bf(p1);
        }
        // rescale O
#pragma unroll
        for (int rg = 0; rg < 4; ++rg) {
            o0[rg] *= al[rg]; o1[rg] *= al[rg]; o2[rg] *= al[rg]; o3[rg] *= al[rg];
        }

        // PV: O[16 q][64 d] += P[16][32] * V[32][64]
        bfrag pa = *(const bfrag*)&Psw[lr][lg * 8];
        bfrag vb0 = *(const bfrag*)&Vs[0  + lr][lg * 8];
        bfrag vb1 = *(const bfrag*)&Vs[16 + lr][lg * 8];
        bfrag vb2 = *(const bfrag*)&Vs[32 + lr][lg * 8];
        bfrag vb3 = *(const bfrag*)&Vs[48 + lr][lg * 8];
        o0 = __builtin_amdgcn_mfma_f32_16x16x32_bf16(pa, vb0, o0, 0, 0, 0);
        o1 = __builtin_amdgcn_mfma_f32_16x16x32_bf16(pa, vb1, o1, 0, 0, 0);
        o2 = __builtin_amdgcn_mfma_f32_16x16x32_bf16(pa, vb2, o2, 0, 0, 0);
        o3 = __builtin_amdgcn_mfma_f32_16x16x32_bf16(pa, vb3, o3, 0, 0, 0);
    }

    // epilogue: normalize, transpose through LDS, coalesced store
    __syncthreads();
    {
        float inv[4];
#pragma unroll
        for (int rg = 0; rg < 4; ++rg) inv[rg] = 1.0f / l[rg];
#pragma unroll
        for (int rg = 0; rg < 4; ++rg) {
            int row = wv * 16 + lg * 4 + rg;
            Os[row][0  + lr] = o0[rg] * inv[rg];
            Os[row][16 + lr] = o1[rg] * inv[rg];
            Os[row][32 + lr] = o2[rg] * inv[rg];
            Os[row][48 + lr] = o3[rg] * inv[rg];
        }
    }
    __syncthreads();
    for (int idx = tid; idx < 4096; idx += 256) {
        int d = idx >> 6, n = idx & 63;
        Yw[((size_t)b * CCH + h * HD + d) * NN + n0 + n] = Os[n][d];
    }
}

// ---------------------------------------------------------------------------
// depthwise 3x3 conv + BN on qcn (fp32), accumulated into Yw
// ---------------------------------------------------------------------------
__global__ __launch_bounds__(256)
void pe_add_kernel(const float* __restrict__ Qf,   // [B][C][N] fp32
                   const float* __restrict__ Wpe,
                   const float* __restrict__ gg, const float* __restrict__ bb,
                   const float* __restrict__ mm, const float* __restrict__ vv,
                   float* __restrict__ Yw)
{
    int idx = blockIdx.x * 256 + threadIdx.x;
    if (idx >= NB * CCH * NN) return;
    int n = idx % NN;
    int x = n % WW, y = n / WW;
    int c = (idx / NN) % CCH;
    const float* src = Qf + (size_t)(idx - n);

    float s    = gg[c] * rsqrtf(vv[c] + EPSBN);
    float bias = bb[c] - mm[c] * s;
    float accv = 0.f;
#pragma unroll
    for (int dy = -1; dy <= 1; ++dy) {
        int yy = y + dy;
        if (yy < 0 || yy >= HH) continue;
#pragma unroll
        for (int dx = -1; dx <= 1; ++dx) {
            int xx = x + dx;
            if (xx < 0 || xx >= WW) continue;
            accv += Wpe[c * 9 + (dy + 1) * 3 + (dx + 1)] * src[yy * WW + xx];
        }
    }
    Yw[idx] += accv * s + bias;
}

// ---------------------------------------------------------------------------
extern "C" void kernel_launch(void* const* d_in, const int* in_sizes, int n_in,
                              void* d_out, int out_size, void* d_ws, size_t ws_size,
                              hipStream_t stream) {
    const float* q      = (const float*)d_in[0];
    const float* k      = (const float*)d_in[1];
    const float* v      = (const float*)d_in[2];
    const float* wq_w   = (const float*)d_in[3];
    const float* wk_w   = (const float*)d_in[4];
    const float* wv_w   = (const float*)d_in[5];
    const float* proj_w = (const float*)d_in[6];
    const float* pe_w   = (const float*)d_in[7];
    const float* wq_g = (const float*)d_in[8],  *wq_b = (const float*)d_in[9];
    const float* wq_m = (const float*)d_in[10], *wq_v = (const float*)d_in[11];
    const float* wk_g = (const float*)d_in[12], *wk_b = (const float*)d_in[13];
    const float* wk_m = (const float*)d_in[14], *wk_v = (const float*)d_in[15];
    const float* wv_g = (const float*)d_in[16], *wv_b = (const float*)d_in[17];
    const float* wv_m = (const float*)d_in[18], *wv_v = (const float*)d_in[19];
    const float* pe_g = (const float*)d_in[20], *pe_b = (const float*)d_in[21];
    const float* pe_m = (const float*)d_in[22], *pe_v = (const float*)d_in[23];
    const float* pj_g = (const float*)d_in[24], *pj_b = (const float*)d_in[25];
    const float* pj_m = (const float*)d_in[26], *pj_v = (const float*)d_in[27];

    const size_t BCN = (size_t)NB * CCH * NN;    // 2,359,296
    float*    qcn = (float*)d_ws;                // fp32 [b][c][n]
    float*    yw  = qcn + BCN;                   // fp32 [b][c][n]
    ushort_t* qnd = (ushort_t*)(yw + BCN);       // bf16 [b][h][n][d] (scaled)
    ushort_t* knd = qnd + BCN;                   // bf16 [b][h][n][d]
    ushort_t* vcn = knd + BCN;                   // bf16 [b][c][n]

    dim3 gConv(NN / 64, CCH / 64, NB);
    conv1x1_bn_kernel<1><<<gConv, 256, 0, stream>>>(q, wq_w, wq_g, wq_b, wq_m, wq_v, qcn, qnd);
    conv1x1_bn_kernel<2><<<gConv, 256, 0, stream>>>(k, wk_w, wk_g, wk_b, wk_m, wk_v, nullptr, knd);
    conv1x1_bn_kernel<3><<<gConv, 256, 0, stream>>>(v, wv_w, wv_g, wv_b, wv_m, wv_v, nullptr, vcn);

    dim3 gAttn(NN / 64, NB * HEADS);
    attn_mfma_kernel<<<gAttn, 256, 0, stream>>>(qnd, knd, vcn, yw);

    int total = NB * CCH * NN;
    pe_add_kernel<<<total / 256, 256, 0, stream>>>(qcn, pe_w, pe_g, pe_b, pe_m, pe_v, yw);

    conv1x1_bn_kernel<0><<<gConv, 256, 0, stream>>>(yw, proj_w, pj_g, pj_b, pj_m, pj_v,
                                                    (float*)d_out, nullptr);
}

// Round 3
// 196.293 us; speedup vs baseline: 4.9643x; 1.5248x over previous
//
#include <hip/hip_runtime.h>
#include <math.h>

#define HEADS 4
#define HD    64
#define CCH   256
#define NB    4
#define HH    48
#define WW    48
#define NN    (HH*WW)      // 2304
#define EPSBN 1e-5f

typedef unsigned short ushort_t;
typedef __attribute__((ext_vector_type(8))) short bfrag;   // 8 bf16 = 4 VGPR
typedef __attribute__((ext_vector_type(4))) float f32x4;   // MFMA C/D

static __device__ __forceinline__ ushort_t f2bf(float x) {
    unsigned int u = __float_as_uint(x);
    unsigned int r = (u + 0x7fffu + ((u >> 16) & 1u)) >> 16;   // RNE
    return (ushort_t)r;
}

// ---------------------------------------------------------------------------
// 1x1 conv + folded BN, fp32 compute, 64x64 tile, 4x4 contiguous micro-tile.
// MODE 0: fp32 [b][c][n] out (proj)
// MODE 1: fp32 [b][c][n] out + bf16 [b][h][n][d] out scaled by 0.125 (q)
// MODE 2: bf16 [b][h][n][d] out (k)
// MODE 3: bf16 [b][c][n] out (v)
// ---------------------------------------------------------------------------
template<int MODE>
__global__ __launch_bounds__(256)
void conv1x1_bn_kernel(const float* __restrict__ X,   // [B][C][N]
                       const float* __restrict__ W,   // [C][C]
                       const float* __restrict__ gg, const float* __restrict__ bb,
                       const float* __restrict__ mm, const float* __restrict__ vv,
                       float* __restrict__ Ycn,
                       ushort_t* __restrict__ Ynd)
{
    __shared__ float Wt[16][68];       // [cc][o], pitch 68 for 16B-aligned float4
    __shared__ float Xt[16][64];       // [cc][n]
    __shared__ ushort_t Ot[64][72];    // bf16 [n][d] staging (MODE 1/2)

    const int nt  = blockIdx.x;
    const int ot  = blockIdx.y;
    const int b   = blockIdx.z;
    const int tid = threadIdx.x;
    const int to  = tid >> 4;          // 0..15 -> o block of 4
    const int tn  = tid & 15;          // 0..15 -> n block of 4
    const int n0  = nt * 64, o0 = ot * 64;
    const float* Xb = X + (size_t)b * CCH * NN;

    float acc[4][4];                   // [i=o][j=n]
#pragma unroll
    for (int i = 0; i < 4; ++i)
#pragma unroll
        for (int j = 0; j < 4; ++j) acc[i][j] = 0.f;

    for (int k0 = 0; k0 < CCH; k0 += 16) {
        {
            int idx = tid;
#pragma unroll
            for (int it = 0; it < 4; ++it, idx += 256) {
                int cc = idx & 15, o = idx >> 4;
                Wt[cc][o] = W[(size_t)(o0 + o) * CCH + k0 + cc];
            }
        }
        {
            int idx = tid;
#pragma unroll
            for (int it = 0; it < 4; ++it, idx += 256) {
                int n = idx & 63, cc = idx >> 6;
                Xt[cc][n] = Xb[(size_t)(k0 + cc) * NN + n0 + n];
            }
        }
        __syncthreads();
#pragma unroll
        for (int cc = 0; cc < 16; ++cc) {
            float4 a4 = *(const float4*)&Wt[cc][to * 4];   // broadcast in quarter-wave
            float4 x4 = *(const float4*)&Xt[cc][tn * 4];
            acc[0][0] += a4.x*x4.x; acc[0][1] += a4.x*x4.y; acc[0][2] += a4.x*x4.z; acc[0][3] += a4.x*x4.w;
            acc[1][0] += a4.y*x4.x; acc[1][1] += a4.y*x4.y; acc[1][2] += a4.y*x4.z; acc[1][3] += a4.y*x4.w;
            acc[2][0] += a4.z*x4.x; acc[2][1] += a4.z*x4.y; acc[2][2] += a4.z*x4.z; acc[2][3] += a4.z*x4.w;
            acc[3][0] += a4.w*x4.x; acc[3][1] += a4.w*x4.y; acc[3][2] += a4.w*x4.z; acc[3][3] += a4.w*x4.w;
        }
        __syncthreads();
    }

#pragma unroll
    for (int i = 0; i < 4; ++i) {
        int o = o0 + to * 4 + i;
        float s    = gg[o] * rsqrtf(vv[o] + EPSBN);
        float bias = bb[o] - mm[o] * s;
        float r0 = acc[i][0] * s + bias;
        float r1 = acc[i][1] * s + bias;
        float r2 = acc[i][2] * s + bias;
        float r3 = acc[i][3] * s + bias;
        if (MODE == 0 || MODE == 1) {
            float4 out = {r0, r1, r2, r3};
            *(float4*)&Ycn[((size_t)b * CCH + o) * NN + n0 + tn * 4] = out;
        }
        if (MODE == 3) {
            uint2 pk;
            pk.x = ((unsigned)f2bf(r1) << 16) | f2bf(r0);
            pk.y = ((unsigned)f2bf(r3) << 16) | f2bf(r2);
            *(uint2*)&Ynd[((size_t)b * CCH + o) * NN + n0 + tn * 4] = pk;
        }
        if (MODE == 1 || MODE == 2) {
            const float sc = (MODE == 1) ? 0.125f : 1.0f;
            Ot[tn * 4 + 0][to * 4 + i] = f2bf(r0 * sc);
            Ot[tn * 4 + 1][to * 4 + i] = f2bf(r1 * sc);
            Ot[tn * 4 + 2][to * 4 + i] = f2bf(r2 * sc);
            Ot[tn * 4 + 3][to * 4 + i] = f2bf(r3 * sc);
        }
    }
    if (MODE == 1 || MODE == 2) {
        __syncthreads();
        for (int idx = tid; idx < 512; idx += 256) {
            int r = idx >> 3, seg = idx & 7;
            *(uint4*)&Ynd[(((size_t)b * HEADS + ot) * NN + n0 + r) * HD + seg * 8] =
                *(const uint4*)&Ot[r][seg * 8];
        }
    }
}

// ---------------------------------------------------------------------------
// MFMA flash attention, transposed-score layout.
// Block = 64 q rows x (b,h); 4 waves x 16 q each. Bc = 64 kv per tile.
// S^T = mfma(K,Q): lane holds one q column -> softmax nearly lane-local.
// O accumulated as O^T[d][q] -> direct coalesced store, no transpose.
// ---------------------------------------------------------------------------
__global__ __launch_bounds__(256)
void attn_mfma_kernel(const ushort_t* __restrict__ Qnd,  // bf16 [b][h][n][d], pre-scaled
                      const ushort_t* __restrict__ Knd,  // bf16 [b][h][n][d]
                      const ushort_t* __restrict__ Vcn,  // bf16 [b][c][n] == V^T per head
                      float* __restrict__ Yw)            // fp32 [b][c][n]
{
    __shared__ __align__(16) ushort_t Ks[64][72];       // [kk][d]
    __shared__ __align__(16) ushort_t Vs[64][72];       // [d][kk]  (= V^T)
    __shared__ __align__(16) ushort_t Ps[4][16][72];    // per wave: [q][kk]

    const int qt   = blockIdx.x;          // 0..35
    const int bh   = blockIdx.y;          // 0..15
    const int b    = bh >> 2, h = bh & 3;
    const int tid  = threadIdx.x;
    const int lane = tid & 63, wv = tid >> 6;
    const int lr   = lane & 15;           // q column (and row idx for A frags)
    const int lg   = lane >> 4;           // k-group 0..3
    const int n0   = qt * 64;
    const size_t ndbase = (size_t)(b * HEADS + h) * NN * HD;
    const size_t cnbase = ((size_t)b * CCH + h * HD) * NN;

    // Q B-fragments (lane = col q), read once from global
    const ushort_t* qrow = Qnd + ndbase + (size_t)(n0 + wv * 16 + lr) * HD;
    bfrag qb0 = *(const bfrag*)&qrow[lg * 8];
    bfrag qb1 = *(const bfrag*)&qrow[32 + lg * 8];

    f32x4 o[4];
#pragma unroll
    for (int db = 0; db < 4; ++db) o[db] = (f32x4){0.f, 0.f, 0.f, 0.f};
    float m = -1e30f, l = 0.f;

    const int r0  = tid >> 3, sg = tid & 7;   // staging coords (512 uint4 / 2 per mat)
    const int r1  = r0 + 32;

    for (int k0 = 0; k0 < NN; k0 += 64) {
        __syncthreads();
        *(uint4*)&Ks[r0][sg * 8] = *(const uint4*)&Knd[ndbase + (size_t)(k0 + r0) * HD + sg * 8];
        *(uint4*)&Ks[r1][sg * 8] = *(const uint4*)&Knd[ndbase + (size_t)(k0 + r1) * HD + sg * 8];
        *(uint4*)&Vs[r0][sg * 8] = *(const uint4*)&Vcn[cnbase + (size_t)r0 * NN + k0 + sg * 8];
        *(uint4*)&Vs[r1][sg * 8] = *(const uint4*)&Vcn[cnbase + (size_t)r1 * NN + k0 + sg * 8];
        __syncthreads();

        // S^T[64 kk][16 q]
        f32x4 st[4];
#pragma unroll
        for (int kb = 0; kb < 4; ++kb) {
            bfrag ka0 = *(const bfrag*)&Ks[kb * 16 + lr][lg * 8];
            bfrag ka1 = *(const bfrag*)&Ks[kb * 16 + lr][32 + lg * 8];
            f32x4 z = (f32x4){0.f, 0.f, 0.f, 0.f};
            z = __builtin_amdgcn_mfma_f32_16x16x32_bf16(ka0, qb0, z, 0, 0, 0);
            z = __builtin_amdgcn_mfma_f32_16x16x32_bf16(ka1, qb1, z, 0, 0, 0);
            st[kb] = z;
        }

        // online softmax: all 16 in-lane values share q = lr
        float mx = st[0][0];
#pragma unroll
        for (int kb = 0; kb < 4; ++kb)
#pragma unroll
            for (int r = 0; r < 4; ++r) mx = fmaxf(mx, st[kb][r]);
        mx = fmaxf(mx, __shfl_xor(mx, 16));
        mx = fmaxf(mx, __shfl_xor(mx, 32));
        float mn    = fmaxf(m, mx);
        float alpha = __expf(m - mn);
        m = mn;
        float ps = 0.f;
#pragma unroll
        for (int kb = 0; kb < 4; ++kb) {
            float p0 = __expf(st[kb][0] - mn);
            float p1 = __expf(st[kb][1] - mn);
            float p2 = __expf(st[kb][2] - mn);
            float p3 = __expf(st[kb][3] - mn);
            ps += (p0 + p1) + (p2 + p3);
            uint2 pk;
            pk.x = ((unsigned)f2bf(p1) << 16) | f2bf(p0);
            pk.y = ((unsigned)f2bf(p3) << 16) | f2bf(p2);
            *(uint2*)&Ps[wv][lr][kb * 16 + lg * 4] = pk;   // P[q][kk], kk=16kb+4lg+r
        }
        ps += __shfl_xor(ps, 16);
        ps += __shfl_xor(ps, 32);
        l = l * alpha + ps;
#pragma unroll
        for (int db = 0; db < 4; ++db) {
            o[db][0] *= alpha; o[db][1] *= alpha; o[db][2] *= alpha; o[db][3] *= alpha;
        }

        // PV: O^T[64 d][16 q] += V^T[64 d][64 kk] * P^T[64 kk][16 q]
        bfrag pb0 = *(const bfrag*)&Ps[wv][lr][lg * 8];        // kk 0..31
        bfrag pb1 = *(const bfrag*)&Ps[wv][lr][32 + lg * 8];   // kk 32..63
#pragma unroll
        for (int db = 0; db < 4; ++db) {
            bfrag va0 = *(const bfrag*)&Vs[db * 16 + lr][lg * 8];
            bfrag va1 = *(const bfrag*)&Vs[db * 16 + lr][32 + lg * 8];
            o[db] = __builtin_amdgcn_mfma_f32_16x16x32_bf16(va0, pb0, o[db], 0, 0, 0);
            o[db] = __builtin_amdgcn_mfma_f32_16x16x32_bf16(va1, pb1, o[db], 0, 0, 0);
        }
    }

    // epilogue: lane = output column n -> coalesced scalar stores, no LDS
    float inv = 1.f / l;
    float* yb = Yw + cnbase + n0 + wv * 16 + lr;
#pragma unroll
    for (int db = 0; db < 4; ++db)
#pragma unroll
        for (int r = 0; r < 4; ++r)
            yb[(size_t)(db * 16 + lg * 4 + r) * NN] = o[db][r] * inv;
}

// ---------------------------------------------------------------------------
// depthwise 3x3 conv + BN on qcn (fp32), accumulated into Yw
// ---------------------------------------------------------------------------
__global__ __launch_bounds__(256)
void pe_add_kernel(const float* __restrict__ Qf,   // [B][C][N] fp32
                   const float* __restrict__ Wpe,
                   const float* __restrict__ gg, const float* __restrict__ bb,
                   const float* __restrict__ mm, const float* __restrict__ vv,
                   float* __restrict__ Yw)
{
    int idx = blockIdx.x * 256 + threadIdx.x;
    if (idx >= NB * CCH * NN) return;
    int n = idx % NN;
    int x = n % WW, y = n / WW;
    int c = (idx / NN) % CCH;
    const float* src = Qf + (size_t)(idx - n);

    float s    = gg[c] * rsqrtf(vv[c] + EPSBN);
    float bias = bb[c] - mm[c] * s;
    float accv = 0.f;
#pragma unroll
    for (int dy = -1; dy <= 1; ++dy) {
        int yy = y + dy;
        if (yy < 0 || yy >= HH) continue;
#pragma unroll
        for (int dx = -1; dx <= 1; ++dx) {
            int xx = x + dx;
            if (xx < 0 || xx >= WW) continue;
            accv += Wpe[c * 9 + (dy + 1) * 3 + (dx + 1)] * src[yy * WW + xx];
        }
    }
    Yw[idx] += accv * s + bias;
}

// ---------------------------------------------------------------------------
extern "C" void kernel_launch(void* const* d_in, const int* in_sizes, int n_in,
                              void* d_out, int out_size, void* d_ws, size_t ws_size,
                              hipStream_t stream) {
    const float* q      = (const float*)d_in[0];
    const float* k      = (const float*)d_in[1];
    const float* v      = (const float*)d_in[2];
    const float* wq_w   = (const float*)d_in[3];
    const float* wk_w   = (const float*)d_in[4];
    const float* wv_w   = (const float*)d_in[5];
    const float* proj_w = (const float*)d_in[6];
    const float* pe_w   = (const float*)d_in[7];
    const float* wq_g = (const float*)d_in[8],  *wq_b = (const float*)d_in[9];
    const float* wq_m = (const float*)d_in[10], *wq_v = (const float*)d_in[11];
    const float* wk_g = (const float*)d_in[12], *wk_b = (const float*)d_in[13];
    const float* wk_m = (const float*)d_in[14], *wk_v = (const float*)d_in[15];
    const float* wv_g = (const float*)d_in[16], *wv_b = (const float*)d_in[17];
    const float* wv_m = (const float*)d_in[18], *wv_v = (const float*)d_in[19];
    const float* pe_g = (const float*)d_in[20], *pe_b = (const float*)d_in[21];
    const float* pe_m = (const float*)d_in[22], *pe_v = (const float*)d_in[23];
    const float* pj_g = (const float*)d_in[24], *pj_b = (const float*)d_in[25];
    const float* pj_m = (const float*)d_in[26], *pj_v = (const float*)d_in[27];

    const size_t BCN = (size_t)NB * CCH * NN;    // 2,359,296
    float*    qcn = (float*)d_ws;                // fp32 [b][c][n]
    float*    yw  = qcn + BCN;                   // fp32 [b][c][n]
    ushort_t* qnd = (ushort_t*)(yw + BCN);       // bf16 [b][h][n][d] (scaled)
    ushort_t* knd = qnd + BCN;                   // bf16 [b][h][n][d]
    ushort_t* vcn = knd + BCN;                   // bf16 [b][c][n]

    dim3 gConv(NN / 64, CCH / 64, NB);
    conv1x1_bn_kernel<1><<<gConv, 256, 0, stream>>>(q, wq_w, wq_g, wq_b, wq_m, wq_v, qcn, qnd);
    conv1x1_bn_kernel<2><<<gConv, 256, 0, stream>>>(k, wk_w, wk_g, wk_b, wk_m, wk_v, nullptr, knd);
    conv1x1_bn_kernel<3><<<gConv, 256, 0, stream>>>(v, wv_w, wv_g, wv_b, wv_m, wv_v, nullptr, vcn);

    dim3 gAttn(NN / 64, NB * HEADS);
    attn_mfma_kernel<<<gAttn, 256, 0, stream>>>(qnd, knd, vcn, yw);

    int total = NB * CCH * NN;
    pe_add_kernel<<<total / 256, 256, 0, stream>>>(qcn, pe_w, pe_g, pe_b, pe_m, pe_v, yw);

    conv1x1_bn_kernel<0><<<gConv, 256, 0, stream>>>(yw, proj_w, pj_g, pj_b, pj_m, pj_v,
                                                    (float*)d_out, nullptr);
}

// Round 4
// 113.513 us; speedup vs baseline: 8.5846x; 1.7293x over previous
//
#include <hip/hip_runtime.h>
#include <math.h>

#define HEADS 4
#define HD    64
#define CCH   256
#define NB    4
#define HH    48
#define WW    48
#define NN    (HH*WW)            // 2304
#define EPSBN 1e-5f
#define KSCL  0.18033688f        // 0.125 * log2(e)  (folded into K weights/bias)
#define BCN   (NB*CCH*NN)        // 2,359,296 elements

typedef unsigned short ushort_t;
typedef __attribute__((ext_vector_type(8))) short bfrag;   // 8 bf16 = 4 VGPR
typedef __attribute__((ext_vector_type(4))) float f32x4;   // MFMA C/D

#define MFMA __builtin_amdgcn_mfma_f32_16x16x32_bf16

static __device__ __forceinline__ ushort_t f2bf(float x) {
    unsigned int u = __float_as_uint(x);
    unsigned int r = (u + 0x7fffu + ((u >> 16) & 1u)) >> 16;   // RNE
    return (ushort_t)r;
}
static __device__ __forceinline__ unsigned cvtpk(float lo, float hi) {
    unsigned r;
    asm("v_cvt_pk_bf16_f32 %0, %1, %2" : "=v"(r) : "v"(lo), "v"(hi));
    return r;
}
static __device__ __forceinline__ float bflo(unsigned u) { return __uint_as_float(u << 16); }
static __device__ __forceinline__ float bfhi(unsigned u) { return __uint_as_float(u & 0xffff0000u); }

// ---------------------------------------------------------------------------
// prep: fp32 [b][c][n] -> bf16 [b][n][c] for q,k,v.  Register transpose:
// 8 coalesced strided loads -> cvt_pk -> one uint4 store. No LDS.
// ---------------------------------------------------------------------------
__global__ __launch_bounds__(256)
void prep_transpose(const float* __restrict__ q, const float* __restrict__ k,
                    const float* __restrict__ v, ushort_t* __restrict__ Xt)
{
    const int blk = blockIdx.x;
    const int t  = blk / 1152;
    const int r  = blk % 1152;
    const int b  = r / 288;
    const int r2 = r % 288;
    const int n0 = (r2 >> 3) * 64;
    const int cb = (r2 & 7) * 32;
    const float* X = (t == 0) ? q : (t == 1) ? k : v;
    ushort_t* O = Xt + (size_t)t * BCN;
    const int lane = threadIdx.x & 63;
    const int c0   = cb + (threadIdx.x >> 6) * 8;
    const float* src = X + ((size_t)(b * CCH + c0) * NN + n0 + lane);
    float vv[8];
#pragma unroll
    for (int j = 0; j < 8; ++j) vv[j] = src[(size_t)j * NN];
    uint4 u;
    u.x = cvtpk(vv[0], vv[1]); u.y = cvtpk(vv[2], vv[3]);
    u.z = cvtpk(vv[4], vv[5]); u.w = cvtpk(vv[6], vv[7]);
    *(uint4*)&O[((size_t)b * NN + n0 + lane) * CCH + c0] = u;
}

// ---------------------------------------------------------------------------
// prep: fold BN into weights -> bf16 W'[4][256][256]; bias'[4][256] fp32.
// conv 1 (K) additionally folds 0.125*log2e. Also pe weights tap-major bf16.
// ---------------------------------------------------------------------------
struct PrepWP {
    const float* W[4];
    const float* G[4]; const float* Bb[4]; const float* Mm[4]; const float* Vv[4];
    const float* pew; const float* peg; const float* peb; const float* pem; const float* pev;
    ushort_t* W4; float* bias4; ushort_t* pw2; float* pbias;
};
__global__ __launch_bounds__(256)
void prep_w(PrepWP P)
{
    const int blk = blockIdx.x, tid = threadIdx.x;
    if (blk == 128) {   // pe weights + bias
        int c = tid;
        float s = P.peg[c] * rsqrtf(P.pev[c] + EPSBN);
        for (int tap = 0; tap < 9; ++tap)
            P.pw2[tap * CCH + c] = f2bf(P.pew[c * 9 + tap] * s);
        P.pbias[c] = P.peb[c] - P.pem[c] * s;
        return;
    }
    int g  = blk * 256 + tid;
    int cv = g >> 13;
    int o  = (g >> 5) & 255;
    int c8 = g & 31;
    float s  = P.G[cv][o] * rsqrtf(P.Vv[cv][o] + EPSBN);
    float s2 = (cv == 1) ? s * KSCL : s;
    const float* w = P.W[cv] + (size_t)o * CCH + c8 * 8;
    uint4 u;
    u.x = cvtpk(w[0]*s2, w[1]*s2); u.y = cvtpk(w[2]*s2, w[3]*s2);
    u.z = cvtpk(w[4]*s2, w[5]*s2); u.w = cvtpk(w[6]*s2, w[7]*s2);
    *(uint4*)&P.W4[((size_t)cv * CCH + o) * CCH + c8 * 8] = u;
    if (c8 == 0) {
        float bb = (P.Bb[cv][o] - P.Mm[cv][o] * s);
        P.bias4[cv * CCH + o] = (cv == 1) ? bb * KSCL : bb;
    }
}

// ---------------------------------------------------------------------------
// bf16 MFMA 1x1-conv GEMM, 64x64 tile, full K=256 staged once.
// T = tensor bf16 [b][n][c], Wp = W' bf16 [o][c] (BN folded), bias fp32.
// V==0: D[n][o] -> bf16 [b][h][n][d]   (q, k)
// V==1: D[o][n] -> bf16 [b][c][n]      (v)
// V==2: D[o][n] -> fp32 [b][c][n]      (proj -> d_out)
// ---------------------------------------------------------------------------
template<int V>
__global__ __launch_bounds__(256)
void conv_gemm(const ushort_t* __restrict__ T, const ushort_t* __restrict__ Wp,
               const float* __restrict__ bias,
               ushort_t* __restrict__ outb, float* __restrict__ outf)
{
    __shared__ ushort_t Ts[64][264];   // pitch 264: 528B rows -> uniform banks
    __shared__ ushort_t Ws[64][264];
    const int nt = blockIdx.x, ot = blockIdx.y, b = blockIdx.z;
    const int tid = threadIdx.x;
    const int n0 = nt * 64, o0 = ot * 64;
    const ushort_t* Tsrc = T + ((size_t)b * NN + n0) * CCH;
    const ushort_t* Wsrc = Wp + (size_t)o0 * CCH;
#pragma unroll
    for (int i = 0; i < 8; ++i) {
        int idx = tid + i * 256;
        int r = idx >> 5, c16 = idx & 31;
        *(uint4*)&Ts[r][c16 * 8] = *(const uint4*)&Tsrc[(size_t)r * CCH + c16 * 8];
        *(uint4*)&Ws[r][c16 * 8] = *(const uint4*)&Wsrc[(size_t)r * CCH + c16 * 8];
    }
    __syncthreads();
    const int wv = tid >> 6, lane = tid & 63, lr = lane & 15, lg = lane >> 4;
    const int qn = (wv >> 1) * 32, qo = (wv & 1) * 32;
    f32x4 acc[2][2];
#pragma unroll
    for (int i = 0; i < 2; ++i)
#pragma unroll
        for (int j = 0; j < 2; ++j) acc[i][j] = (f32x4){0.f, 0.f, 0.f, 0.f};

#pragma unroll
    for (int k8 = 0; k8 < 8; ++k8) {
        const int kc = k8 * 32 + lg * 8;
        bfrag ta0 = *(const bfrag*)&Ts[qn + lr][kc];
        bfrag ta1 = *(const bfrag*)&Ts[qn + 16 + lr][kc];
        bfrag wa0 = *(const bfrag*)&Ws[qo + lr][kc];
        bfrag wa1 = *(const bfrag*)&Ws[qo + 16 + lr][kc];
        if (V == 0) {   // D[n][o]
            acc[0][0] = MFMA(ta0, wa0, acc[0][0], 0, 0, 0);
            acc[0][1] = MFMA(ta0, wa1, acc[0][1], 0, 0, 0);
            acc[1][0] = MFMA(ta1, wa0, acc[1][0], 0, 0, 0);
            acc[1][1] = MFMA(ta1, wa1, acc[1][1], 0, 0, 0);
        } else {        // D[o][n]
            acc[0][0] = MFMA(wa0, ta0, acc[0][0], 0, 0, 0);
            acc[0][1] = MFMA(wa0, ta1, acc[0][1], 0, 0, 0);
            acc[1][0] = MFMA(wa1, ta0, acc[1][0], 0, 0, 0);
            acc[1][1] = MFMA(wa1, ta1, acc[1][1], 0, 0, 0);
        }
    }

    if (V == 0) {
        const int h = ot;   // 64-channel o-tile == head
        float bv[2] = { bias[o0 + qo + lr], bias[o0 + qo + 16 + lr] };
#pragma unroll
        for (int i = 0; i < 2; ++i)
#pragma unroll
            for (int j = 0; j < 2; ++j)
#pragma unroll
                for (int r = 0; r < 4; ++r) {
                    int n = n0 + qn + i * 16 + lg * 4 + r;
                    int d = qo + j * 16 + lr;
                    outb[(((size_t)b * HEADS + h) * NN + n) * HD + d] =
                        f2bf(acc[i][j][r] + bv[j]);
                }
    } else {
        float bv[2][4];
#pragma unroll
        for (int i = 0; i < 2; ++i)
#pragma unroll
            for (int r = 0; r < 4; ++r)
                bv[i][r] = bias[o0 + qo + i * 16 + lg * 4 + r];
#pragma unroll
        for (int i = 0; i < 2; ++i)
#pragma unroll
            for (int j = 0; j < 2; ++j)
#pragma unroll
                for (int r = 0; r < 4; ++r) {
                    int o = o0 + qo + i * 16 + lg * 4 + r;
                    int n = n0 + qn + j * 16 + lr;
                    float val = acc[i][j][r] + bv[i][r];
                    size_t a = ((size_t)b * CCH + o) * NN + n;
                    if (V == 1) outb[a] = f2bf(val);
                    else        outf[a] = val;
                }
    }
}

// ---------------------------------------------------------------------------
// MFMA flash attention, kv-split x2, exp2-domain, defer-max.
// Block = 64 q rows x (b,h) x split; 4 waves x 16 q. Bc = 64 kv per tile.
// Writes unnormalized O' fp32 [s][b][n][c] + m,l per q-row.
// ---------------------------------------------------------------------------
__global__ __launch_bounds__(256)
void attn_kernel(const ushort_t* __restrict__ Qnd,  // bf16 [b][h][n][d] unscaled
                 const ushort_t* __restrict__ Knd,  // bf16 [b][h][n][d] *KSCL
                 const ushort_t* __restrict__ Vcn,  // bf16 [b][c][n]
                 float* __restrict__ Op,            // fp32 [2][b][n][c]
                 float* __restrict__ Marr, float* __restrict__ Larr)
{
    __shared__ __align__(16) char smem[27648];
    ushort_t (*Ks)[72] = (ushort_t(*)[72])(smem);            // [64][72]
    ushort_t (*Vs)[72] = (ushort_t(*)[72])(smem + 9216);     // [64][72]

    const int qt = blockIdx.x, bh = blockIdx.y, sp = blockIdx.z;
    const int b = bh >> 2, h = bh & 3;
    const int tid = threadIdx.x, lane = tid & 63, wv = tid >> 6;
    const int lr = lane & 15, lg = lane >> 4;
    const int n0 = qt * 64;
    const size_t ndb = (size_t)(b * HEADS + h) * NN * HD;
    const size_t cnb = ((size_t)b * CCH + h * HD) * NN;
    ushort_t (*Psw)[72] = (ushort_t(*)[72])(smem + 18432 + wv * 2304); // [16][72]

    const ushort_t* qrow = Qnd + ndb + (size_t)(n0 + wv * 16 + lr) * HD;
    bfrag qb0 = *(const bfrag*)&qrow[lg * 8];
    bfrag qb1 = *(const bfrag*)&qrow[32 + lg * 8];

    f32x4 o[4];
#pragma unroll
    for (int db = 0; db < 4; ++db) o[db] = (f32x4){0.f, 0.f, 0.f, 0.f};
    float m = -1e30f, l = 0.f;
    const int r0 = tid >> 3, sg = tid & 7, r1 = r0 + 32;
    const int kb0 = sp * (NN / 2);

    for (int t = 0; t < 18; ++t) {
        const int k0 = kb0 + t * 64;
        __syncthreads();
        *(uint4*)&Ks[r0][sg * 8] = *(const uint4*)&Knd[ndb + (size_t)(k0 + r0) * HD + sg * 8];
        *(uint4*)&Ks[r1][sg * 8] = *(const uint4*)&Knd[ndb + (size_t)(k0 + r1) * HD + sg * 8];
        *(uint4*)&Vs[r0][sg * 8] = *(const uint4*)&Vcn[cnb + (size_t)r0 * NN + k0 + sg * 8];
        *(uint4*)&Vs[r1][sg * 8] = *(const uint4*)&Vcn[cnb + (size_t)r1 * NN + k0 + sg * 8];
        __syncthreads();

        // S^T[64 kk][16 q] in exp2 domain (scale folded into K)
        f32x4 st[4];
#pragma unroll
        for (int kb = 0; kb < 4; ++kb) {
            bfrag ka0 = *(const bfrag*)&Ks[kb * 16 + lr][lg * 8];
            bfrag ka1 = *(const bfrag*)&Ks[kb * 16 + lr][32 + lg * 8];
            f32x4 z = (f32x4){0.f, 0.f, 0.f, 0.f};
            z = MFMA(ka0, qb0, z, 0, 0, 0);
            z = MFMA(ka1, qb1, z, 0, 0, 0);
            st[kb] = z;
        }

        float t0 = fmaxf(fmaxf(st[0][0], st[0][1]), fmaxf(st[0][2], st[0][3]));
        float t1 = fmaxf(fmaxf(st[1][0], st[1][1]), fmaxf(st[1][2], st[1][3]));
        float t2 = fmaxf(fmaxf(st[2][0], st[2][1]), fmaxf(st[2][2], st[2][3]));
        float t3 = fmaxf(fmaxf(st[3][0], st[3][1]), fmaxf(st[3][2], st[3][3]));
        float mx = fmaxf(fmaxf(t0, t1), fmaxf(t2, t3));
        mx = fmaxf(mx, __shfl_xor(mx, 16));
        mx = fmaxf(mx, __shfl_xor(mx, 32));
        float alpha = 1.0f;
        if (__any(mx > m + 8.0f)) {      // defer-max: rescale only on real growth
            float mn = fmaxf(m, mx);
            alpha = exp2f(m - mn);
            m = mn;
#pragma unroll
            for (int db = 0; db < 4; ++db) {
                o[db][0] *= alpha; o[db][1] *= alpha;
                o[db][2] *= alpha; o[db][3] *= alpha;
            }
        }
        float ps = 0.f;
#pragma unroll
        for (int kb = 0; kb < 4; ++kb) {
            float p0 = exp2f(st[kb][0] - m), p1 = exp2f(st[kb][1] - m);
            float p2 = exp2f(st[kb][2] - m), p3 = exp2f(st[kb][3] - m);
            ps += (p0 + p1) + (p2 + p3);
            uint2 u; u.x = cvtpk(p0, p1); u.y = cvtpk(p2, p3);
            *(uint2*)&Psw[lr][kb * 16 + lg * 4] = u;   // P[q][kk]
        }
        ps += __shfl_xor(ps, 16);
        ps += __shfl_xor(ps, 32);
        l = l * alpha + ps;

        bfrag pb0 = *(const bfrag*)&Psw[lr][lg * 8];
        bfrag pb1 = *(const bfrag*)&Psw[lr][32 + lg * 8];
#pragma unroll
        for (int db = 0; db < 4; ++db) {
            bfrag va0 = *(const bfrag*)&Vs[db * 16 + lr][lg * 8];
            bfrag va1 = *(const bfrag*)&Vs[db * 16 + lr][32 + lg * 8];
            o[db] = MFMA(va0, pb0, o[db], 0, 0, 0);
            o[db] = MFMA(va1, pb1, o[db], 0, 0, 0);
        }
    }

    // epilogue: transpose O^T[d][q] -> [n][c] via LDS (pitch 65: ~2-way free)
    __syncthreads();
    float (*Os)[65] = (float(*)[65])(smem);
    {
        int row = wv * 16 + lr;
#pragma unroll
        for (int db = 0; db < 4; ++db)
#pragma unroll
            for (int r = 0; r < 4; ++r)
                Os[row][db * 16 + lg * 4 + r] = o[db][r];
    }
    if (lg == 0) {
        int gi = (sp * 16 + bh) * NN + n0 + wv * 16 + lr;
        Marr[gi] = m; Larr[gi] = l;
    }
    __syncthreads();
    {
        int nn = tid >> 2, qq = tid & 3;
        float* op = Op + (size_t)sp * BCN + ((size_t)b * NN + n0 + nn) * CCH + h * HD + qq * 16;
#pragma unroll
        for (int j4 = 0; j4 < 4; ++j4) {
            float4 v4 = { Os[nn][qq * 16 + j4 * 4 + 0], Os[nn][qq * 16 + j4 * 4 + 1],
                          Os[nn][qq * 16 + j4 * 4 + 2], Os[nn][qq * 16 + j4 * 4 + 3] };
            *(float4*)&op[j4 * 4] = v4;
        }
    }
}

// ---------------------------------------------------------------------------
// fuse: combine kv-splits + depthwise 3x3 BN (bf16) -> bf16 [b][n][c] for proj
// ---------------------------------------------------------------------------
__global__ __launch_bounds__(256)
void fuse_kernel(const float* __restrict__ Op, const float* __restrict__ Marr,
                 const float* __restrict__ Larr, const ushort_t* __restrict__ Qnd,
                 const ushort_t* __restrict__ pw2, const float* __restrict__ pbias,
                 ushort_t* __restrict__ yt)
{
    const int tid = threadIdx.x;
    const int b  = blockIdx.x / 288;
    const int n0 = (blockIdx.x % 288) * 8;
    const int c8 = tid & 31, ns = tid >> 5;
    const int n  = n0 + ns;
    const int h  = c8 >> 3, c0 = c8 * 8;

    const float* o0p = Op + ((size_t)b * NN + n) * CCH + c0;
    const float* o1p = o0p + (size_t)BCN;
    float4 a0 = *(const float4*)o0p, a1 = *(const float4*)(o0p + 4);
    float4 b0 = *(const float4*)o1p, b1 = *(const float4*)(o1p + 4);
    int mi = (b * HEADS + h) * NN + n;
    float m0 = Marr[mi], l0 = Larr[mi];
    float m1 = Marr[16 * NN + mi], l1 = Larr[16 * NN + mi];
    float M  = fmaxf(m0, m1);
    float e0 = exp2f(m0 - M), e1 = exp2f(m1 - M);
    float rinv = 1.0f / (l0 * e0 + l1 * e1);
    float acc[8];
    acc[0] = (a0.x * e0 + b0.x * e1) * rinv;  acc[1] = (a0.y * e0 + b0.y * e1) * rinv;
    acc[2] = (a0.z * e0 + b0.z * e1) * rinv;  acc[3] = (a0.w * e0 + b0.w * e1) * rinv;
    acc[4] = (a1.x * e0 + b1.x * e1) * rinv;  acc[5] = (a1.y * e0 + b1.y * e1) * rinv;
    acc[6] = (a1.z * e0 + b1.z * e1) * rinv;  acc[7] = (a1.w * e0 + b1.w * e1) * rinv;

    // depthwise 3x3 (zero-pad) on q-features, bf16
    const int x = n % WW, y = n / WW;
    const ushort_t* qb = Qnd + (size_t)(b * HEADS + h) * NN * HD + (c8 & 7) * 8;
#pragma unroll
    for (int ky = 0; ky < 3; ++ky) {
        int yy = y + ky - 1;
        if (yy < 0 || yy >= HH) continue;
#pragma unroll
        for (int kx = 0; kx < 3; ++kx) {
            int xx = x + kx - 1;
            if (xx < 0 || xx >= WW) continue;
            int np = yy * WW + xx;
            uint4 qv = *(const uint4*)&qb[(size_t)np * HD];
            uint4 w4 = *(const uint4*)&pw2[(ky * 3 + kx) * CCH + c0];
            acc[0] += bflo(qv.x) * bflo(w4.x); acc[1] += bfhi(qv.x) * bfhi(w4.x);
            acc[2] += bflo(qv.y) * bflo(w4.y); acc[3] += bfhi(qv.y) * bfhi(w4.y);
            acc[4] += bflo(qv.z) * bflo(w4.z); acc[5] += bfhi(qv.z) * bfhi(w4.z);
            acc[6] += bflo(qv.w) * bflo(w4.w); acc[7] += bfhi(qv.w) * bfhi(w4.w);
        }
    }
    float4 p0 = *(const float4*)&pbias[c0];
    float4 p1 = *(const float4*)&pbias[c0 + 4];
    acc[0] += p0.x; acc[1] += p0.y; acc[2] += p0.z; acc[3] += p0.w;
    acc[4] += p1.x; acc[5] += p1.y; acc[6] += p1.z; acc[7] += p1.w;
    uint4 u;
    u.x = cvtpk(acc[0], acc[1]); u.y = cvtpk(acc[2], acc[3]);
    u.z = cvtpk(acc[4], acc[5]); u.w = cvtpk(acc[6], acc[7]);
    *(uint4*)&yt[((size_t)b * NN + n) * CCH + c0] = u;
}

// ---------------------------------------------------------------------------
extern "C" void kernel_launch(void* const* d_in, const int* in_sizes, int n_in,
                              void* d_out, int out_size, void* d_ws, size_t ws_size,
                              hipStream_t stream) {
    const float* q = (const float*)d_in[0];
    const float* k = (const float*)d_in[1];
    const float* v = (const float*)d_in[2];

    char* ws = (char*)d_ws;
    // layout (bytes): qnd@0, knd@4.72M, vcn@9.44M, Xt(3)@14.16M,
    // O'(2x fp32, alias Xt)@14.16M..33.03M, yt(alias knd)@4.72M,
    // Marr/Larr@33.03M, W4/bias/pe@33.62M  (total ~34.2 MB)
    ushort_t* qnd  = (ushort_t*)(ws + 0);
    ushort_t* knd  = (ushort_t*)(ws + 4718592);
    ushort_t* vcn  = (ushort_t*)(ws + 9437184);
    ushort_t* Xt   = (ushort_t*)(ws + 14155776);
    float*    O0   = (float*)   (ws + 14155776);
    ushort_t* yt   = (ushort_t*)(ws + 4718592);
    float*    Marr = (float*)   (ws + 33030144);
    float*    Larr = (float*)   (ws + 33325056);
    ushort_t* W4   = (ushort_t*)(ws + 33619968);
    float*    bias4= (float*)   (ws + 34144256);
    ushort_t* pw2  = (ushort_t*)(ws + 34148352);
    float*    pbias= (float*)   (ws + 34152960);

    prep_transpose<<<3456, 256, 0, stream>>>(q, k, v, Xt);

    PrepWP P;
    P.W[0] = (const float*)d_in[3]; P.W[1] = (const float*)d_in[4];
    P.W[2] = (const float*)d_in[5]; P.W[3] = (const float*)d_in[6];
    P.G[0]  = (const float*)d_in[8];  P.Bb[0] = (const float*)d_in[9];
    P.Mm[0] = (const float*)d_in[10]; P.Vv[0] = (const float*)d_in[11];
    P.G[1]  = (const float*)d_in[12]; P.Bb[1] = (const float*)d_in[13];
    P.Mm[1] = (const float*)d_in[14]; P.Vv[1] = (const float*)d_in[15];
    P.G[2]  = (const float*)d_in[16]; P.Bb[2] = (const float*)d_in[17];
    P.Mm[2] = (const float*)d_in[18]; P.Vv[2] = (const float*)d_in[19];
    P.G[3]  = (const float*)d_in[24]; P.Bb[3] = (const float*)d_in[25];
    P.Mm[3] = (const float*)d_in[26]; P.Vv[3] = (const float*)d_in[27];
    P.pew = (const float*)d_in[7];
    P.peg = (const float*)d_in[20]; P.peb = (const float*)d_in[21];
    P.pem = (const float*)d_in[22]; P.pev = (const float*)d_in[23];
    P.W4 = W4; P.bias4 = bias4; P.pw2 = pw2; P.pbias = pbias;
    prep_w<<<129, 256, 0, stream>>>(P);

    dim3 gc(36, 4, 4);
    conv_gemm<0><<<gc, 256, 0, stream>>>(Xt,               W4,          bias4,       qnd, nullptr);
    conv_gemm<0><<<gc, 256, 0, stream>>>(Xt + (size_t)BCN, W4 + 65536,  bias4 + 256, knd, nullptr);
    conv_gemm<1><<<gc, 256, 0, stream>>>(Xt + 2*(size_t)BCN, W4 + 131072, bias4 + 512, vcn, nullptr);

    attn_kernel<<<dim3(36, 16, 2), 256, 0, stream>>>(qnd, knd, vcn, O0, Marr, Larr);

    fuse_kernel<<<1152, 256, 0, stream>>>(O0, Marr, Larr, qnd, pw2, pbias, yt);

    conv_gemm<2><<<gc, 256, 0, stream>>>(yt, W4 + 196608, bias4 + 768, nullptr, (float*)d_out);
}

// Round 6
// 106.741 us; speedup vs baseline: 9.1292x; 1.0634x over previous
//
#include <hip/hip_runtime.h>
#include <math.h>

#define HEADS 4
#define HD    64
#define CCH   256
#define NB    4
#define HH    48
#define WW    48
#define NN    (HH*WW)            // 2304
#define EPSBN 1e-5f
#define KSCL  0.18033688f        // 0.125 * log2(e)  (folded into K weights/bias)
#define BCN   (NB*CCH*NN)        // 2,359,296 elements

typedef unsigned short ushort_t;
typedef __attribute__((ext_vector_type(8))) short bfrag;   // 8 bf16 = 4 VGPR
typedef __attribute__((ext_vector_type(4))) float f32x4;   // MFMA C/D

#define MFMA __builtin_amdgcn_mfma_f32_16x16x32_bf16

static __device__ __forceinline__ ushort_t f2bf(float x) {
    unsigned int u = __float_as_uint(x);
    unsigned int r = (u + 0x7fffu + ((u >> 16) & 1u)) >> 16;   // RNE
    return (ushort_t)r;
}
static __device__ __forceinline__ unsigned cvtpk(float lo, float hi) {
    unsigned r;
    asm("v_cvt_pk_bf16_f32 %0, %1, %2" : "=v"(r) : "v"(lo), "v"(hi));
    return r;
}
static __device__ __forceinline__ float bflo(unsigned u) { return __uint_as_float(u << 16); }
static __device__ __forceinline__ float bfhi(unsigned u) { return __uint_as_float(u & 0xffff0000u); }

static __device__ __forceinline__ void gload16(const void* g, void* l) {
    __builtin_amdgcn_global_load_lds(
        (const __attribute__((address_space(1))) void*)g,
        (__attribute__((address_space(3))) void*)l, 16, 0, 0);
}

// ---------------------------------------------------------------------------
// prep: fp32 [b][c][n] -> bf16 [b][n][c] for q,k,v (register transpose)
// ---------------------------------------------------------------------------
__global__ __launch_bounds__(256)
void prep_transpose(const float* __restrict__ q, const float* __restrict__ k,
                    const float* __restrict__ v, ushort_t* __restrict__ Xt)
{
    const int blk = blockIdx.x;
    const int t  = blk / 1152;
    const int r  = blk % 1152;
    const int b  = r / 288;
    const int r2 = r % 288;
    const int n0 = (r2 >> 3) * 64;
    const int cb = (r2 & 7) * 32;
    const float* X = (t == 0) ? q : (t == 1) ? k : v;
    ushort_t* O = Xt + (size_t)t * BCN;
    const int lane = threadIdx.x & 63;
    const int c0   = cb + (threadIdx.x >> 6) * 8;
    const float* src = X + ((size_t)(b * CCH + c0) * NN + n0 + lane);
    float vv[8];
#pragma unroll
    for (int j = 0; j < 8; ++j) vv[j] = src[(size_t)j * NN];
    uint4 u;
    u.x = cvtpk(vv[0], vv[1]); u.y = cvtpk(vv[2], vv[3]);
    u.z = cvtpk(vv[4], vv[5]); u.w = cvtpk(vv[6], vv[7]);
    *(uint4*)&O[((size_t)b * NN + n0 + lane) * CCH + c0] = u;
}

// ---------------------------------------------------------------------------
// prep: fold BN into weights -> bf16 W'[4][256][256]; bias'[4][256] fp32.
// ---------------------------------------------------------------------------
struct PrepWP {
    const float* W[4];
    const float* G[4]; const float* Bb[4]; const float* Mm[4]; const float* Vv[4];
    const float* pew; const float* peg; const float* peb; const float* pem; const float* pev;
    ushort_t* W4; float* bias4; ushort_t* pw2; float* pbias;
};
__global__ __launch_bounds__(256)
void prep_w(PrepWP P)
{
    const int blk = blockIdx.x, tid = threadIdx.x;
    if (blk == 128) {
        int c = tid;
        float s = P.peg[c] * rsqrtf(P.pev[c] + EPSBN);
        for (int tap = 0; tap < 9; ++tap)
            P.pw2[tap * CCH + c] = f2bf(P.pew[c * 9 + tap] * s);
        P.pbias[c] = P.peb[c] - P.pem[c] * s;
        return;
    }
    int g  = blk * 256 + tid;
    int cv = g >> 13;
    int o  = (g >> 5) & 255;
    int c8 = g & 31;
    float s  = P.G[cv][o] * rsqrtf(P.Vv[cv][o] + EPSBN);
    float s2 = (cv == 1) ? s * KSCL : s;
    const float* w = P.W[cv] + (size_t)o * CCH + c8 * 8;
    uint4 u;
    u.x = cvtpk(w[0]*s2, w[1]*s2); u.y = cvtpk(w[2]*s2, w[3]*s2);
    u.z = cvtpk(w[4]*s2, w[5]*s2); u.w = cvtpk(w[6]*s2, w[7]*s2);
    *(uint4*)&P.W4[((size_t)cv * CCH + o) * CCH + c8 * 8] = u;
    if (c8 == 0) {
        float bb = (P.Bb[cv][o] - P.Mm[cv][o] * s);
        P.bias4[cv * CCH + o] = (cv == 1) ? bb * KSCL : bb;
    }
}

// ---------------------------------------------------------------------------
// bf16 MFMA 1x1-conv GEMM, 64x64 tile, full K=256 staged once.
// PROJ==0: z = which*4+b, which 0(q),1(k) -> bf16 [b][h][n][d]; 2(v) -> bf16 [b][c][n]
// PROJ==1: which=3, fp32 [b][c][n] -> d_out
// ---------------------------------------------------------------------------
template<int PROJ>
__global__ __launch_bounds__(256)
void conv_gemm(const ushort_t* __restrict__ T, const ushort_t* __restrict__ W4,
               const float* __restrict__ bias4,
               ushort_t* __restrict__ qnd, ushort_t* __restrict__ knd,
               ushort_t* __restrict__ vcn, float* __restrict__ outf)
{
    __shared__ ushort_t Ts[64][264];
    __shared__ ushort_t Ws[64][264];
    const int nt = blockIdx.x, ot = blockIdx.y, z = blockIdx.z;
    const int which = PROJ ? 3 : (z >> 2);
    const int b = z & 3;
    const int tid = threadIdx.x;
    const int n0 = nt * 64, o0 = ot * 64;
    const ushort_t* Tsrc = T + (PROJ ? (size_t)0 : (size_t)which * BCN) + ((size_t)b * NN + n0) * CCH;
    const ushort_t* Wsrc = W4 + (size_t)which * CCH * CCH + (size_t)o0 * CCH;
    const float*    bias = bias4 + which * CCH;
#pragma unroll
    for (int i = 0; i < 8; ++i) {
        int idx = tid + i * 256;
        int r = idx >> 5, c16 = idx & 31;
        *(uint4*)&Ts[r][c16 * 8] = *(const uint4*)&Tsrc[(size_t)r * CCH + c16 * 8];
        *(uint4*)&Ws[r][c16 * 8] = *(const uint4*)&Wsrc[(size_t)r * CCH + c16 * 8];
    }
    __syncthreads();
    const int wv = tid >> 6, lane = tid & 63, lr = lane & 15, lg = lane >> 4;
    const int qn = (wv >> 1) * 32, qo = (wv & 1) * 32;
    f32x4 acc[2][2];
#pragma unroll
    for (int i = 0; i < 2; ++i)
#pragma unroll
        for (int j = 0; j < 2; ++j) acc[i][j] = (f32x4){0.f, 0.f, 0.f, 0.f};

    if (!PROJ) {
        if ((z >> 2) < 2) {
#pragma unroll
            for (int k8 = 0; k8 < 8; ++k8) {
                const int kc = k8 * 32 + lg * 8;
                bfrag ta0 = *(const bfrag*)&Ts[qn + lr][kc];
                bfrag ta1 = *(const bfrag*)&Ts[qn + 16 + lr][kc];
                bfrag wa0 = *(const bfrag*)&Ws[qo + lr][kc];
                bfrag wa1 = *(const bfrag*)&Ws[qo + 16 + lr][kc];
                acc[0][0] = MFMA(ta0, wa0, acc[0][0], 0, 0, 0);
                acc[0][1] = MFMA(ta0, wa1, acc[0][1], 0, 0, 0);
                acc[1][0] = MFMA(ta1, wa0, acc[1][0], 0, 0, 0);
                acc[1][1] = MFMA(ta1, wa1, acc[1][1], 0, 0, 0);
            }
        } else {
#pragma unroll
            for (int k8 = 0; k8 < 8; ++k8) {
                const int kc = k8 * 32 + lg * 8;
                bfrag ta0 = *(const bfrag*)&Ts[qn + lr][kc];
                bfrag ta1 = *(const bfrag*)&Ts[qn + 16 + lr][kc];
                bfrag wa0 = *(const bfrag*)&Ws[qo + lr][kc];
                bfrag wa1 = *(const bfrag*)&Ws[qo + 16 + lr][kc];
                acc[0][0] = MFMA(wa0, ta0, acc[0][0], 0, 0, 0);
                acc[0][1] = MFMA(wa0, ta1, acc[0][1], 0, 0, 0);
                acc[1][0] = MFMA(wa1, ta0, acc[1][0], 0, 0, 0);
                acc[1][1] = MFMA(wa1, ta1, acc[1][1], 0, 0, 0);
            }
        }
    } else {
#pragma unroll
        for (int k8 = 0; k8 < 8; ++k8) {
            const int kc = k8 * 32 + lg * 8;
            bfrag ta0 = *(const bfrag*)&Ts[qn + lr][kc];
            bfrag ta1 = *(const bfrag*)&Ts[qn + 16 + lr][kc];
            bfrag wa0 = *(const bfrag*)&Ws[qo + lr][kc];
            bfrag wa1 = *(const bfrag*)&Ws[qo + 16 + lr][kc];
            acc[0][0] = MFMA(wa0, ta0, acc[0][0], 0, 0, 0);
            acc[0][1] = MFMA(wa0, ta1, acc[0][1], 0, 0, 0);
            acc[1][0] = MFMA(wa1, ta0, acc[1][0], 0, 0, 0);
            acc[1][1] = MFMA(wa1, ta1, acc[1][1], 0, 0, 0);
        }
    }

    __syncthreads();   // Ts/Ws dead; overlay epilogue staging
    if (!PROJ && which < 2) {
        ushort_t (*Ot)[72] = (ushort_t(*)[72])Ts;
        float bv[2] = { bias[o0 + qo + lr], bias[o0 + qo + 16 + lr] };   // FIX: +o0
#pragma unroll
        for (int i = 0; i < 2; ++i)
#pragma unroll
            for (int j = 0; j < 2; ++j)
#pragma unroll
                for (int r = 0; r < 4; ++r)
                    Ot[qn + i * 16 + lg * 4 + r][qo + j * 16 + lr] = f2bf(acc[i][j][r] + bv[j]);
        __syncthreads();
        ushort_t* out = (which == 0) ? qnd : knd;
        for (int idx = tid; idx < 512; idx += 256) {
            int r = idx >> 3, sg = idx & 7;
            *(uint4*)&out[(((size_t)b * HEADS + ot) * NN + n0 + r) * HD + sg * 8] =
                *(const uint4*)&Ot[r][sg * 8];
        }
    } else if (!PROJ) {
        ushort_t (*Ot)[72] = (ushort_t(*)[72])Ts;
#pragma unroll
        for (int i = 0; i < 2; ++i)
#pragma unroll
            for (int r = 0; r < 4; ++r) {
                float bv = bias[o0 + qo + i * 16 + lg * 4 + r];          // FIX: +o0
#pragma unroll
                for (int j = 0; j < 2; ++j)
                    Ot[qo + i * 16 + lg * 4 + r][qn + j * 16 + lr] = f2bf(acc[i][j][r] + bv);
            }
        __syncthreads();
        for (int idx = tid; idx < 512; idx += 256) {
            int r = idx >> 3, sg = idx & 7;
            *(uint4*)&vcn[((size_t)b * CCH + o0 + r) * NN + n0 + sg * 8] =
                *(const uint4*)&Ot[r][sg * 8];
        }
    } else {
        float (*Of)[68] = (float(*)[68])Ts;
#pragma unroll
        for (int i = 0; i < 2; ++i)
#pragma unroll
            for (int r = 0; r < 4; ++r) {
                float bv = bias[o0 + qo + i * 16 + lg * 4 + r];          // FIX: +o0
#pragma unroll
                for (int j = 0; j < 2; ++j)
                    Of[qo + i * 16 + lg * 4 + r][qn + j * 16 + lr] = acc[i][j][r] + bv;
            }
        __syncthreads();
        for (int idx = tid; idx < 1024; idx += 256) {
            int r = idx >> 4, c4 = idx & 15;
            *(float4*)&outf[((size_t)b * CCH + o0 + r) * NN + n0 + c4 * 4] =
                *(const float4*)&Of[r][c4 * 4];
        }
    }
}

// ---------------------------------------------------------------------------
// per-head max row-norm of K' (KSCL-folded): kmax[bh] = max_n |k'_n|
// ---------------------------------------------------------------------------
__global__ __launch_bounds__(256)
void knorm_kernel(const ushort_t* __restrict__ knd, float* __restrict__ kmax)
{
    __shared__ float red[4];
    const int bh = blockIdx.x;
    const ushort_t* base = knd + (size_t)bh * NN * HD;
    float mx = 0.f;
    for (int i = threadIdx.x; i < NN; i += 256) {
        const uint4* row = (const uint4*)(base + (size_t)i * HD);
        float s = 0.f;
#pragma unroll
        for (int j = 0; j < 8; ++j) {
            uint4 u = row[j];
            s += bflo(u.x)*bflo(u.x) + bfhi(u.x)*bfhi(u.x);
            s += bflo(u.y)*bflo(u.y) + bfhi(u.y)*bfhi(u.y);
            s += bflo(u.z)*bflo(u.z) + bfhi(u.z)*bfhi(u.z);
            s += bflo(u.w)*bflo(u.w) + bfhi(u.w)*bfhi(u.w);
        }
        mx = fmaxf(mx, s);
    }
#pragma unroll
    for (int d = 1; d < 64; d <<= 1) mx = fmaxf(mx, __shfl_xor(mx, d));
    if ((threadIdx.x & 63) == 0) red[threadIdx.x >> 6] = mx;
    __syncthreads();
    if (threadIdx.x == 0)
        kmax[bh] = sqrtf(fmaxf(fmaxf(red[0], red[1]), fmaxf(red[2], red[3])));
}

// ---------------------------------------------------------------------------
// MFMA flash attention: 4 waves x 32 q = 128 q rows/block, Bc=64, kv-split x2.
// Norm-bound fixed softmax max (no reductions in loop); l via ones-row MFMA.
// K/V staged via global_load_lds with pre-swizzled source; XOR-swizzled LDS.
// ---------------------------------------------------------------------------
__global__ __launch_bounds__(256, 3)
void attn_kernel(const ushort_t* __restrict__ Qnd,   // bf16 [b][h][n][d]
                 const ushort_t* __restrict__ Knd,   // bf16 [b][h][n][d] *KSCL
                 const ushort_t* __restrict__ Vcn,   // bf16 [b][c][n]
                 const float* __restrict__ kmax,     // [16]
                 float* __restrict__ Op,             // fp32 [2][b][n][c]
                 float* __restrict__ Larr)           // fp32 [2][16][NN]
{
    __shared__ __align__(16) char smem[49152];
    // K2 @0: [2][64][64]sw ; V2 @16384: [2][64][64]sw ; Ps @32768: [4][32][64]sw

    const int tid = threadIdx.x;
    const int lin0 = blockIdx.x + 18 * blockIdx.y + 288 * blockIdx.z;
    const int w    = (lin0 & 7) * 72 + (lin0 >> 3);   // XCD-chunked remap (576=8*72)
    const int qt = w % 18;
    const int bh = (w / 18) & 15;
    const int sp = w / 288;
    const int b = bh >> 2, h = bh & 3;
    const int lane = tid & 63, wv = tid >> 6;
    const int lr = lane & 15, lg = lane >> 4;
    const int lrow = lane >> 3, lslot = (lane & 7) ^ lrow;
    const int n0 = qt * 128;
    const size_t ndb = (size_t)(b * HEADS + h) * NN * HD;
    const size_t cnb = ((size_t)b * CCH + h * HD) * NN;

    // staging pointers (pre-swizzled global source, linear LDS dest)
    const char* kgp = (const char*)(Knd + ndb) + (size_t)(sp * 1152 + wv * 16 + lrow) * 128 + lslot * 16;
    const char* vgp = (const char*)(Vcn + cnb + sp * 1152) + (size_t)(wv * 16 + lrow) * (NN * 2) + lslot * 16;
    char* kls = smem + wv * 2048;
    char* vls = smem + 16384 + wv * 2048;

#define STAGE(buf, t) do { \
    const char* kp_ = kgp + (size_t)(t) * 8192; \
    const char* vp_ = vgp + (size_t)(t) * 128; \
    char* kd_ = kls + (buf) * 8192; \
    char* vd_ = vls + (buf) * 8192; \
    gload16(kp_,               kd_); \
    gload16(kp_ + 1024,        kd_ + 1024); \
    gload16(vp_,               vd_); \
    gload16(vp_ + 8 * (NN*2),  vd_ + 1024); \
} while (0)

    // Q fragments (32 q rows per wave)
    bfrag qb[2][2];
    {
        const ushort_t* qbase = Qnd + ndb + (size_t)(n0 + wv * 32 + lr) * HD;
        qb[0][0] = *(const bfrag*)&qbase[lg * 8];
        qb[0][1] = *(const bfrag*)&qbase[32 + lg * 8];
        qb[1][0] = *(const bfrag*)&qbase[16 * HD + lg * 8];
        qb[1][1] = *(const bfrag*)&qbase[16 * HD + 32 + lg * 8];
    }
    // fixed softmax bound m0 = |q| * max|k'| + margin
    float m0[2];
    {
        const float kmx = kmax[bh];
#pragma unroll
        for (int qc = 0; qc < 2; ++qc) {
            const unsigned* u0 = (const unsigned*)&qb[qc][0];
            const unsigned* u1 = (const unsigned*)&qb[qc][1];
            float s = 0.f;
#pragma unroll
            for (int j = 0; j < 4; ++j) {
                float a0 = bflo(u0[j]), a1 = bfhi(u0[j]);
                float b0 = bflo(u1[j]), b1 = bfhi(u1[j]);
                s += a0*a0 + a1*a1 + b0*b0 + b1*b1;
            }
            s += __shfl_xor(s, 16);
            s += __shfl_xor(s, 32);
            m0[qc] = sqrtf(s) * kmx + 0.5f;
        }
    }
    // ones A-fragment (row 0 = 1.0, rows 1..15 = 0) for l accumulation
    bfrag ones_f;
    {
        short ov = (lr == 0) ? (short)0x3F80 : (short)0;
#pragma unroll
        for (int j = 0; j < 8; ++j) ones_f[j] = ov;
    }

    f32x4 o[2][4], o4[2];
#pragma unroll
    for (int qc = 0; qc < 2; ++qc) {
        o4[qc] = (f32x4){0.f, 0.f, 0.f, 0.f};
#pragma unroll
        for (int db = 0; db < 4; ++db) o[qc][db] = (f32x4){0.f, 0.f, 0.f, 0.f};
    }

    char* Pw = smem + 32768 + wv * 4096;   // wave's P: [32 q][64 kk] swizzled
    const int sw0 = (lg ^ (lr & 7)) << 4;
    const int sw1 = ((4 + lg) ^ (lr & 7)) << 4;

    STAGE(0, 0);
    __syncthreads();

    for (int t = 0; t < 18; ++t) {
        const int cur = t & 1;
        if (t < 17) STAGE(cur ^ 1, t + 1);           // prefetch (drained at barrier)
        const char* Kb = smem + cur * 8192;
        const char* Vb = smem + 16384 + cur * 8192;

        // S^T[64 kk][32 q]
        f32x4 st[2][4];
#pragma unroll
        for (int kb = 0; kb < 4; ++kb) {
            const char* krow = Kb + (kb * 16 + lr) * 128;
            bfrag ka0 = *(const bfrag*)(krow + sw0);
            bfrag ka1 = *(const bfrag*)(krow + sw1);
            f32x4 z0 = (f32x4){0.f, 0.f, 0.f, 0.f};
            z0 = MFMA(ka0, qb[0][0], z0, 0, 0, 0);
            st[0][kb] = MFMA(ka1, qb[0][1], z0, 0, 0, 0);
            f32x4 z1 = (f32x4){0.f, 0.f, 0.f, 0.f};
            z1 = MFMA(ka0, qb[1][0], z1, 0, 0, 0);
            st[1][kb] = MFMA(ka1, qb[1][1], z1, 0, 0, 0);
        }

        // p = 2^(s - m0); no reductions needed
#pragma unroll
        for (int qc = 0; qc < 2; ++qc) {
            const float mm = m0[qc];
            char* prow = Pw + (qc * 16 + lr) * 128;
#pragma unroll
            for (int kb = 0; kb < 4; ++kb) {
                float p0 = exp2f(st[qc][kb][0] - mm);
                float p1 = exp2f(st[qc][kb][1] - mm);
                float p2 = exp2f(st[qc][kb][2] - mm);
                float p3 = exp2f(st[qc][kb][3] - mm);
                uint2 u; u.x = cvtpk(p0, p1); u.y = cvtpk(p2, p3);
                int slot = (2 * kb + (lg >> 1)) ^ (lr & 7);
                *(uint2*)(prow + slot * 16 + (lg & 1) * 8) = u;
            }
        }

        // PV: O^T[d][q] += V^T * P^T ; l via ones row
        bfrag pb[2][2];
#pragma unroll
        for (int qc = 0; qc < 2; ++qc) {
            const char* prow = Pw + (qc * 16 + lr) * 128;
            pb[qc][0] = *(const bfrag*)(prow + sw0);
            pb[qc][1] = *(const bfrag*)(prow + sw1);
        }
#pragma unroll
        for (int db = 0; db < 4; ++db) {
            const char* vrow = Vb + (db * 16 + lr) * 128;
            bfrag va0 = *(const bfrag*)(vrow + sw0);
            bfrag va1 = *(const bfrag*)(vrow + sw1);
            o[0][db] = MFMA(va0, pb[0][0], o[0][db], 0, 0, 0);
            o[0][db] = MFMA(va1, pb[0][1], o[0][db], 0, 0, 0);
            o[1][db] = MFMA(va0, pb[1][0], o[1][db], 0, 0, 0);
            o[1][db] = MFMA(va1, pb[1][1], o[1][db], 0, 0, 0);
        }
        o4[0] = MFMA(ones_f, pb[0][0], o4[0], 0, 0, 0);
        o4[0] = MFMA(ones_f, pb[0][1], o4[0], 0, 0, 0);
        o4[1] = MFMA(ones_f, pb[1][0], o4[1], 0, 0, 0);
        o4[1] = MFMA(ones_f, pb[1][1], o4[1], 0, 0, 0);

        __syncthreads();   // drains prefetch vmcnt + protects buffers
    }
#undef STAGE

    // epilogue: O^T -> [n][c] via LDS transpose; write unnormalized O' + l
    if (lg == 0) {
#pragma unroll
        for (int qc = 0; qc < 2; ++qc)
            Larr[(size_t)(sp * 16 + bh) * NN + n0 + wv * 32 + qc * 16 + lr] = o4[qc][0];
    }
    float (*Os)[68] = (float(*)[68])smem;   // [128][68]
#pragma unroll
    for (int qc = 0; qc < 2; ++qc) {
        int row = wv * 32 + qc * 16 + lr;
#pragma unroll
        for (int db = 0; db < 4; ++db)
#pragma unroll
            for (int r = 0; r < 4; ++r)
                Os[row][db * 16 + lg * 4 + r] = o[qc][db][r];
    }
    __syncthreads();
    float* opb = Op + (size_t)sp * BCN + ((size_t)b * NN + n0) * CCH + h * HD;
    for (int idx = tid; idx < 2048; idx += 256) {
        int n = idx >> 4, c4 = idx & 15;
        *(float4*)&opb[(size_t)n * CCH + c4 * 4] = *(const float4*)&Os[n][c4 * 4];
    }
}

// ---------------------------------------------------------------------------
// fuse: combine kv-splits + depthwise 3x3 BN (bf16) -> bf16 [b][n][c] for proj
// ---------------------------------------------------------------------------
__global__ __launch_bounds__(256)
void fuse_kernel(const float* __restrict__ Op, const float* __restrict__ Larr,
                 const ushort_t* __restrict__ Qnd,
                 const ushort_t* __restrict__ pw2, const float* __restrict__ pbias,
                 ushort_t* __restrict__ yt)
{
    const int tid = threadIdx.x;
    const int b  = blockIdx.x / 288;
    const int n0 = (blockIdx.x % 288) * 8;
    const int c8 = tid & 31, ns = tid >> 5;
    const int n  = n0 + ns;
    const int h  = c8 >> 3, c0 = c8 * 8;

    const float* o0p = Op + ((size_t)b * NN + n) * CCH + c0;
    const float* o1p = o0p + (size_t)BCN;
    float4 a0 = *(const float4*)o0p, a1 = *(const float4*)(o0p + 4);
    float4 b0 = *(const float4*)o1p, b1 = *(const float4*)(o1p + 4);
    int mi = (b * HEADS + h) * NN + n;
    float rinv = 1.0f / (Larr[mi] + Larr[16 * NN + mi]);
    float acc[8];
    acc[0] = (a0.x + b0.x) * rinv;  acc[1] = (a0.y + b0.y) * rinv;
    acc[2] = (a0.z + b0.z) * rinv;  acc[3] = (a0.w + b0.w) * rinv;
    acc[4] = (a1.x + b1.x) * rinv;  acc[5] = (a1.y + b1.y) * rinv;
    acc[6] = (a1.z + b1.z) * rinv;  acc[7] = (a1.w + b1.w) * rinv;

    const int x = n % WW, y = n / WW;
    const ushort_t* qb = Qnd + (size_t)(b * HEADS + h) * NN * HD + (c8 & 7) * 8;
#pragma unroll
    for (int ky = 0; ky < 3; ++ky) {
        int yy = y + ky - 1;
        if (yy < 0 || yy >= HH) continue;
#pragma unroll
        for (int kx = 0; kx < 3; ++kx) {
            int xx = x + kx - 1;
            if (xx < 0 || xx >= WW) continue;
            int np = yy * WW + xx;
            uint4 qv = *(const uint4*)&qb[(size_t)np * HD];
            uint4 w4 = *(const uint4*)&pw2[(ky * 3 + kx) * CCH + c0];
            acc[0] += bflo(qv.x) * bflo(w4.x); acc[1] += bfhi(qv.x) * bfhi(w4.x);
            acc[2] += bflo(qv.y) * bflo(w4.y); acc[3] += bfhi(qv.y) * bfhi(w4.y);
            acc[4] += bflo(qv.z) * bflo(w4.z); acc[5] += bfhi(qv.z) * bfhi(w4.z);
            acc[6] += bflo(qv.w) * bflo(w4.w); acc[7] += bfhi(qv.w) * bfhi(w4.w);
        }
    }
    float4 p0 = *(const float4*)&pbias[c0];
    float4 p1 = *(const float4*)&pbias[c0 + 4];
    acc[0] += p0.x; acc[1] += p0.y; acc[2] += p0.z; acc[3] += p0.w;
    acc[4] += p1.x; acc[5] += p1.y; acc[6] += p1.z; acc[7] += p1.w;
    uint4 u;
    u.x = cvtpk(acc[0], acc[1]); u.y = cvtpk(acc[2], acc[3]);
    u.z = cvtpk(acc[4], acc[5]); u.w = cvtpk(acc[6], acc[7]);
    *(uint4*)&yt[((size_t)b * NN + n) * CCH + c0] = u;
}

// ---------------------------------------------------------------------------
extern "C" void kernel_launch(void* const* d_in, const int* in_sizes, int n_in,
                              void* d_out, int out_size, void* d_ws, size_t ws_size,
                              hipStream_t stream) {
    const float* q = (const float*)d_in[0];
    const float* k = (const float*)d_in[1];
    const float* v = (const float*)d_in[2];

    char* ws = (char*)d_ws;
    ushort_t* qnd  = (ushort_t*)(ws + 0);
    ushort_t* knd  = (ushort_t*)(ws + 4718592);
    ushort_t* vcn  = (ushort_t*)(ws + 9437184);
    ushort_t* Xt   = (ushort_t*)(ws + 14155776);
    float*    Op   = (float*)   (ws + 14155776);   // overlays Xt after convs
    ushort_t* yt   = (ushort_t*)(ws + 4718592);    // overlays knd after attn
    float*    Larr = (float*)   (ws + 33030144);
    ushort_t* W4   = (ushort_t*)(ws + 33325056);
    float*    bias4= (float*)   (ws + 33849344);
    ushort_t* pw2  = (ushort_t*)(ws + 33853440);
    float*    pbias= (float*)   (ws + 33858048);
    float*    kmax = (float*)   (ws + 33859072);

    prep_transpose<<<3456, 256, 0, stream>>>(q, k, v, Xt);

    PrepWP P;
    P.W[0] = (const float*)d_in[3]; P.W[1] = (const float*)d_in[4];
    P.W[2] = (const float*)d_in[5]; P.W[3] = (const float*)d_in[6];
    P.G[0]  = (const float*)d_in[8];  P.Bb[0] = (const float*)d_in[9];
    P.Mm[0] = (const float*)d_in[10]; P.Vv[0] = (const float*)d_in[11];
    P.G[1]  = (const float*)d_in[12]; P.Bb[1] = (const float*)d_in[13];
    P.Mm[1] = (const float*)d_in[14]; P.Vv[1] = (const float*)d_in[15];
    P.G[2]  = (const float*)d_in[16]; P.Bb[2] = (const float*)d_in[17];
    P.Mm[2] = (const float*)d_in[18]; P.Vv[2] = (const float*)d_in[19];
    P.G[3]  = (const float*)d_in[24]; P.Bb[3] = (const float*)d_in[25];
    P.Mm[3] = (const float*)d_in[26]; P.Vv[3] = (const float*)d_in[27];
    P.pew = (const float*)d_in[7];
    P.peg = (const float*)d_in[20]; P.peb = (const float*)d_in[21];
    P.pem = (const float*)d_in[22]; P.pev = (const float*)d_in[23];
    P.W4 = W4; P.bias4 = bias4; P.pw2 = pw2; P.pbias = pbias;
    prep_w<<<129, 256, 0, stream>>>(P);

    conv_gemm<0><<<dim3(36, 4, 12), 256, 0, stream>>>(Xt, W4, bias4, qnd, knd, vcn, nullptr);

    knorm_kernel<<<16, 256, 0, stream>>>(knd, kmax);

    attn_kernel<<<dim3(18, 16, 2), 256, 0, stream>>>(qnd, knd, vcn, kmax, Op, Larr);

    fuse_kernel<<<1152, 256, 0, stream>>>(Op, Larr, qnd, pw2, pbias, yt);

    conv_gemm<1><<<dim3(36, 4, 4), 256, 0, stream>>>(yt, W4, bias4, nullptr, nullptr, nullptr,
                                                     (float*)d_out);
}

// Round 7
// 98.977 us; speedup vs baseline: 9.8454x; 1.0784x over previous
//
#include <hip/hip_runtime.h>
#include <math.h>

#define HEADS 4
#define HD    64
#define CCH   256
#define NB    4
#define HH    48
#define WW    48
#define NN    (HH*WW)            // 2304
#define EPSBN 1e-5f
#define KSCL  0.18033688f        // 0.125 * log2(e)  (folded into K weights/bias)
#define BCN   (NB*CCH*NN)        // 2,359,296 elements
#define NSP   4                  // kv splits

typedef unsigned short ushort_t;
typedef __attribute__((ext_vector_type(8))) short bfrag;   // 8 bf16 = 4 VGPR
typedef __attribute__((ext_vector_type(4))) float f32x4;   // MFMA C/D

#define MFMA __builtin_amdgcn_mfma_f32_16x16x32_bf16

static __device__ __forceinline__ ushort_t f2bf(float x) {
    unsigned int u = __float_as_uint(x);
    unsigned int r = (u + 0x7fffu + ((u >> 16) & 1u)) >> 16;   // RNE
    return (ushort_t)r;
}
static __device__ __forceinline__ unsigned cvtpk(float lo, float hi) {
    unsigned r;
    asm("v_cvt_pk_bf16_f32 %0, %1, %2" : "=v"(r) : "v"(lo), "v"(hi));
    return r;
}
static __device__ __forceinline__ float bflo(unsigned u) { return __uint_as_float(u << 16); }
static __device__ __forceinline__ float bfhi(unsigned u) { return __uint_as_float(u & 0xffff0000u); }

static __device__ __forceinline__ void gload16(const void* g, void* l) {
    __builtin_amdgcn_global_load_lds(
        (const __attribute__((address_space(1))) void*)g,
        (__attribute__((address_space(3))) void*)l, 16, 0, 0);
}

// ---------------------------------------------------------------------------
// prep: fp32 [b][c][n] -> bf16 [b][n][c] for q,k,v (register transpose)
// ---------------------------------------------------------------------------
__global__ __launch_bounds__(256)
void prep_transpose(const float* __restrict__ q, const float* __restrict__ k,
                    const float* __restrict__ v, ushort_t* __restrict__ Xt)
{
    const int blk = blockIdx.x;
    const int t  = blk / 1152;
    const int r  = blk % 1152;
    const int b  = r / 288;
    const int r2 = r % 288;
    const int n0 = (r2 >> 3) * 64;
    const int cb = (r2 & 7) * 32;
    const float* X = (t == 0) ? q : (t == 1) ? k : v;
    ushort_t* O = Xt + (size_t)t * BCN;
    const int lane = threadIdx.x & 63;
    const int c0   = cb + (threadIdx.x >> 6) * 8;
    const float* src = X + ((size_t)(b * CCH + c0) * NN + n0 + lane);
    float vv[8];
#pragma unroll
    for (int j = 0; j < 8; ++j) vv[j] = src[(size_t)j * NN];
    uint4 u;
    u.x = cvtpk(vv[0], vv[1]); u.y = cvtpk(vv[2], vv[3]);
    u.z = cvtpk(vv[4], vv[5]); u.w = cvtpk(vv[6], vv[7]);
    *(uint4*)&O[((size_t)b * NN + n0 + lane) * CCH + c0] = u;
}

// ---------------------------------------------------------------------------
// prep: fold BN into weights -> bf16 W'[4][256][256]; bias'[4][256] fp32.
// ---------------------------------------------------------------------------
struct PrepWP {
    const float* W[4];
    const float* G[4]; const float* Bb[4]; const float* Mm[4]; const float* Vv[4];
    const float* pew; const float* peg; const float* peb; const float* pem; const float* pev;
    ushort_t* W4; float* bias4; ushort_t* pw2; float* pbias;
};
__global__ __launch_bounds__(256)
void prep_w(PrepWP P)
{
    const int blk = blockIdx.x, tid = threadIdx.x;
    if (blk == 128) {
        int c = tid;
        float s = P.peg[c] * rsqrtf(P.pev[c] + EPSBN);
        for (int tap = 0; tap < 9; ++tap)
            P.pw2[tap * CCH + c] = f2bf(P.pew[c * 9 + tap] * s);
        P.pbias[c] = P.peb[c] - P.pem[c] * s;
        return;
    }
    int g  = blk * 256 + tid;
    int cv = g >> 13;
    int o  = (g >> 5) & 255;
    int c8 = g & 31;
    float s  = P.G[cv][o] * rsqrtf(P.Vv[cv][o] + EPSBN);
    float s2 = (cv == 1) ? s * KSCL : s;
    const float* w = P.W[cv] + (size_t)o * CCH + c8 * 8;
    uint4 u;
    u.x = cvtpk(w[0]*s2, w[1]*s2); u.y = cvtpk(w[2]*s2, w[3]*s2);
    u.z = cvtpk(w[4]*s2, w[5]*s2); u.w = cvtpk(w[6]*s2, w[7]*s2);
    *(uint4*)&P.W4[((size_t)cv * CCH + o) * CCH + c8 * 8] = u;
    if (c8 == 0) {
        float bb = (P.Bb[cv][o] - P.Mm[cv][o] * s);
        P.bias4[cv * CCH + o] = (cv == 1) ? bb * KSCL : bb;
    }
}

// ---------------------------------------------------------------------------
// bf16 MFMA 1x1-conv GEMM, 64x64 tile, full K=256 staged once.
// PROJ==0: z = which*4+b, which 0(q),1(k) -> bf16 [b][h][n][d]; 2(v) -> bf16 [b][c][n]
// PROJ==1: which=3, fp32 [b][c][n] -> d_out
// ---------------------------------------------------------------------------
template<int PROJ>
__global__ __launch_bounds__(256)
void conv_gemm(const ushort_t* __restrict__ T, const ushort_t* __restrict__ W4,
               const float* __restrict__ bias4,
               ushort_t* __restrict__ qnd, ushort_t* __restrict__ knd,
               ushort_t* __restrict__ vcn, float* __restrict__ outf)
{
    __shared__ ushort_t Ts[64][264];
    __shared__ ushort_t Ws[64][264];
    const int nt = blockIdx.x, ot = blockIdx.y, z = blockIdx.z;
    const int which = PROJ ? 3 : (z >> 2);
    const int b = z & 3;
    const int tid = threadIdx.x;
    const int n0 = nt * 64, o0 = ot * 64;
    const ushort_t* Tsrc = T + (PROJ ? (size_t)0 : (size_t)which * BCN) + ((size_t)b * NN + n0) * CCH;
    const ushort_t* Wsrc = W4 + (size_t)which * CCH * CCH + (size_t)o0 * CCH;
    const float*    bias = bias4 + which * CCH;
#pragma unroll
    for (int i = 0; i < 8; ++i) {
        int idx = tid + i * 256;
        int r = idx >> 5, c16 = idx & 31;
        *(uint4*)&Ts[r][c16 * 8] = *(const uint4*)&Tsrc[(size_t)r * CCH + c16 * 8];
        *(uint4*)&Ws[r][c16 * 8] = *(const uint4*)&Wsrc[(size_t)r * CCH + c16 * 8];
    }
    __syncthreads();
    const int wv = tid >> 6, lane = tid & 63, lr = lane & 15, lg = lane >> 4;
    const int qn = (wv >> 1) * 32, qo = (wv & 1) * 32;
    f32x4 acc[2][2];
#pragma unroll
    for (int i = 0; i < 2; ++i)
#pragma unroll
        for (int j = 0; j < 2; ++j) acc[i][j] = (f32x4){0.f, 0.f, 0.f, 0.f};

    if (!PROJ) {
        if ((z >> 2) < 2) {
#pragma unroll
            for (int k8 = 0; k8 < 8; ++k8) {
                const int kc = k8 * 32 + lg * 8;
                bfrag ta0 = *(const bfrag*)&Ts[qn + lr][kc];
                bfrag ta1 = *(const bfrag*)&Ts[qn + 16 + lr][kc];
                bfrag wa0 = *(const bfrag*)&Ws[qo + lr][kc];
                bfrag wa1 = *(const bfrag*)&Ws[qo + 16 + lr][kc];
                acc[0][0] = MFMA(ta0, wa0, acc[0][0], 0, 0, 0);
                acc[0][1] = MFMA(ta0, wa1, acc[0][1], 0, 0, 0);
                acc[1][0] = MFMA(ta1, wa0, acc[1][0], 0, 0, 0);
                acc[1][1] = MFMA(ta1, wa1, acc[1][1], 0, 0, 0);
            }
        } else {
#pragma unroll
            for (int k8 = 0; k8 < 8; ++k8) {
                const int kc = k8 * 32 + lg * 8;
                bfrag ta0 = *(const bfrag*)&Ts[qn + lr][kc];
                bfrag ta1 = *(const bfrag*)&Ts[qn + 16 + lr][kc];
                bfrag wa0 = *(const bfrag*)&Ws[qo + lr][kc];
                bfrag wa1 = *(const bfrag*)&Ws[qo + 16 + lr][kc];
                acc[0][0] = MFMA(wa0, ta0, acc[0][0], 0, 0, 0);
                acc[0][1] = MFMA(wa0, ta1, acc[0][1], 0, 0, 0);
                acc[1][0] = MFMA(wa1, ta0, acc[1][0], 0, 0, 0);
                acc[1][1] = MFMA(wa1, ta1, acc[1][1], 0, 0, 0);
            }
        }
    } else {
#pragma unroll
        for (int k8 = 0; k8 < 8; ++k8) {
            const int kc = k8 * 32 + lg * 8;
            bfrag ta0 = *(const bfrag*)&Ts[qn + lr][kc];
            bfrag ta1 = *(const bfrag*)&Ts[qn + 16 + lr][kc];
            bfrag wa0 = *(const bfrag*)&Ws[qo + lr][kc];
            bfrag wa1 = *(const bfrag*)&Ws[qo + 16 + lr][kc];
            acc[0][0] = MFMA(wa0, ta0, acc[0][0], 0, 0, 0);
            acc[0][1] = MFMA(wa0, ta1, acc[0][1], 0, 0, 0);
            acc[1][0] = MFMA(wa1, ta0, acc[1][0], 0, 0, 0);
            acc[1][1] = MFMA(wa1, ta1, acc[1][1], 0, 0, 0);
        }
    }

    __syncthreads();   // Ts/Ws dead; overlay epilogue staging
    if (!PROJ && which < 2) {
        ushort_t (*Ot)[72] = (ushort_t(*)[72])Ts;
        float bv[2] = { bias[o0 + qo + lr], bias[o0 + qo + 16 + lr] };
#pragma unroll
        for (int i = 0; i < 2; ++i)
#pragma unroll
            for (int j = 0; j < 2; ++j)
#pragma unroll
                for (int r = 0; r < 4; ++r)
                    Ot[qn + i * 16 + lg * 4 + r][qo + j * 16 + lr] = f2bf(acc[i][j][r] + bv[j]);
        __syncthreads();
        ushort_t* out = (which == 0) ? qnd : knd;
        for (int idx = tid; idx < 512; idx += 256) {
            int r = idx >> 3, sg = idx & 7;
            *(uint4*)&out[(((size_t)b * HEADS + ot) * NN + n0 + r) * HD + sg * 8] =
                *(const uint4*)&Ot[r][sg * 8];
        }
    } else if (!PROJ) {
        ushort_t (*Ot)[72] = (ushort_t(*)[72])Ts;
#pragma unroll
        for (int i = 0; i < 2; ++i)
#pragma unroll
            for (int r = 0; r < 4; ++r) {
                float bv = bias[o0 + qo + i * 16 + lg * 4 + r];
#pragma unroll
                for (int j = 0; j < 2; ++j)
                    Ot[qo + i * 16 + lg * 4 + r][qn + j * 16 + lr] = f2bf(acc[i][j][r] + bv);
            }
        __syncthreads();
        for (int idx = tid; idx < 512; idx += 256) {
            int r = idx >> 3, sg = idx & 7;
            *(uint4*)&vcn[((size_t)b * CCH + o0 + r) * NN + n0 + sg * 8] =
                *(const uint4*)&Ot[r][sg * 8];
        }
    } else {
        float (*Of)[68] = (float(*)[68])Ts;
#pragma unroll
        for (int i = 0; i < 2; ++i)
#pragma unroll
            for (int r = 0; r < 4; ++r) {
                float bv = bias[o0 + qo + i * 16 + lg * 4 + r];
#pragma unroll
                for (int j = 0; j < 2; ++j)
                    Of[qo + i * 16 + lg * 4 + r][qn + j * 16 + lr] = acc[i][j][r] + bv;
            }
        __syncthreads();
        for (int idx = tid; idx < 1024; idx += 256) {
            int r = idx >> 4, c4 = idx & 15;
            *(float4*)&outf[((size_t)b * CCH + o0 + r) * NN + n0 + c4 * 4] =
                *(const float4*)&Of[r][c4 * 4];
        }
    }
}

// ---------------------------------------------------------------------------
// per-head max row-norm of K' (KSCL-folded): kmax[bh] = max_n |k'_n|
// ---------------------------------------------------------------------------
__global__ __launch_bounds__(256)
void knorm_kernel(const ushort_t* __restrict__ knd, float* __restrict__ kmax)
{
    __shared__ float red[4];
    const int bh = blockIdx.x;
    const ushort_t* base = knd + (size_t)bh * NN * HD;
    float mx = 0.f;
    for (int i = threadIdx.x; i < NN; i += 256) {
        const uint4* row = (const uint4*)(base + (size_t)i * HD);
        float s = 0.f;
#pragma unroll
        for (int j = 0; j < 8; ++j) {
            uint4 u = row[j];
            s += bflo(u.x)*bflo(u.x) + bfhi(u.x)*bfhi(u.x);
            s += bflo(u.y)*bflo(u.y) + bfhi(u.y)*bfhi(u.y);
            s += bflo(u.z)*bflo(u.z) + bfhi(u.z)*bfhi(u.z);
            s += bflo(u.w)*bflo(u.w) + bfhi(u.w)*bfhi(u.w);
        }
        mx = fmaxf(mx, s);
    }
#pragma unroll
    for (int d = 1; d < 64; d <<= 1) mx = fmaxf(mx, __shfl_xor(mx, d));
    if ((threadIdx.x & 63) == 0) red[threadIdx.x >> 6] = mx;
    __syncthreads();
    if (threadIdx.x == 0)
        kmax[bh] = sqrtf(fmaxf(fmaxf(red[0], red[1]), fmaxf(red[2], red[3])));
}

// ---------------------------------------------------------------------------
// MFMA flash attention: 4 waves x 32 q = 128 q rows/block, Bc=64, kv-split x4.
// Norm-bound fixed softmax max folded into MFMA C-init; l via ones-row MFMA.
// K/V staged via global_load_lds with pre-swizzled source; XOR-swizzled LDS.
// O' written bf16 (m0 split-independent -> plain sum in fuse).
// ---------------------------------------------------------------------------
__global__ __launch_bounds__(256, 3)
void attn_kernel(const ushort_t* __restrict__ Qnd,   // bf16 [b][h][n][d]
                 const ushort_t* __restrict__ Knd,   // bf16 [b][h][n][d] *KSCL
                 const ushort_t* __restrict__ Vcn,   // bf16 [b][c][n]
                 const float* __restrict__ kmax,     // [16]
                 ushort_t* __restrict__ Op,          // bf16 [4][b][n][c]
                 float* __restrict__ Larr)           // fp32 [4][16][NN]
{
    __shared__ __align__(16) char smem[49152];
    // K2 @0: [2][64][64]sw ; V2 @16384: [2][64][64]sw ; Ps @32768: [4][32][64]sw

    const int tid = threadIdx.x;
    const int lin0 = blockIdx.x + 18 * blockIdx.y + 288 * blockIdx.z;
    const int w    = (lin0 & 7) * 144 + (lin0 >> 3);   // XCD-chunked remap (1152=8*144)
    const int qt = w % 18;
    const int bh = (w / 18) & 15;
    const int sp = w / 288;
    const int b = bh >> 2, h = bh & 3;
    const int lane = tid & 63, wv = tid >> 6;
    const int lr = lane & 15, lg = lane >> 4;
    const int lrow = lane >> 3, lslot = (lane & 7) ^ lrow;
    const int n0 = qt * 128;
    const size_t ndb = (size_t)(b * HEADS + h) * NN * HD;
    const size_t cnb = ((size_t)b * CCH + h * HD) * NN;

    // staging pointers (pre-swizzled global source, linear LDS dest)
    const char* kgp = (const char*)(Knd + ndb) + (size_t)(sp * 576 + wv * 16 + lrow) * 128 + lslot * 16;
    const char* vgp = (const char*)(Vcn + cnb + sp * 576) + (size_t)(wv * 16 + lrow) * (NN * 2) + lslot * 16;
    char* kls = smem + wv * 2048;
    char* vls = smem + 16384 + wv * 2048;

#define STAGE(buf, t) do { \
    const char* kp_ = kgp + (size_t)(t) * 8192; \
    const char* vp_ = vgp + (size_t)(t) * 128; \
    char* kd_ = kls + (buf) * 8192; \
    char* vd_ = vls + (buf) * 8192; \
    gload16(kp_,               kd_); \
    gload16(kp_ + 1024,        kd_ + 1024); \
    gload16(vp_,               vd_); \
    gload16(vp_ + 8 * (NN*2),  vd_ + 1024); \
} while (0)

    // Q fragments (32 q rows per wave)
    bfrag qb[2][2];
    {
        const ushort_t* qbase = Qnd + ndb + (size_t)(n0 + wv * 32 + lr) * HD;
        qb[0][0] = *(const bfrag*)&qbase[lg * 8];
        qb[0][1] = *(const bfrag*)&qbase[32 + lg * 8];
        qb[1][0] = *(const bfrag*)&qbase[16 * HD + lg * 8];
        qb[1][1] = *(const bfrag*)&qbase[16 * HD + 32 + lg * 8];
    }
    // fixed softmax bound m0 = |q| * max|k'| + margin
    float m0[2];
    {
        const float kmx = kmax[bh];
#pragma unroll
        for (int qc = 0; qc < 2; ++qc) {
            const unsigned* u0 = (const unsigned*)&qb[qc][0];
            const unsigned* u1 = (const unsigned*)&qb[qc][1];
            float s = 0.f;
#pragma unroll
            for (int j = 0; j < 4; ++j) {
                float a0 = bflo(u0[j]), a1 = bfhi(u0[j]);
                float b0 = bflo(u1[j]), b1 = bfhi(u1[j]);
                s += a0*a0 + a1*a1 + b0*b0 + b1*b1;
            }
            s += __shfl_xor(s, 16);
            s += __shfl_xor(s, 32);
            m0[qc] = sqrtf(s) * kmx + 0.5f;
        }
    }
    // ones A-fragment (row 0 = 1.0, rows 1..15 = 0) for l accumulation
    bfrag ones_f;
    {
        short ov = (lr == 0) ? (short)0x3F80 : (short)0;
#pragma unroll
        for (int j = 0; j < 8; ++j) ones_f[j] = ov;
    }

    f32x4 o[2][4], o4[2];
#pragma unroll
    for (int qc = 0; qc < 2; ++qc) {
        o4[qc] = (f32x4){0.f, 0.f, 0.f, 0.f};
#pragma unroll
        for (int db = 0; db < 4; ++db) o[qc][db] = (f32x4){0.f, 0.f, 0.f, 0.f};
    }

    char* Pw = smem + 32768 + wv * 4096;   // wave's P: [32 q][64 kk] swizzled
    const int sw0 = (lg ^ (lr & 7)) << 4;
    const int sw1 = ((4 + lg) ^ (lr & 7)) << 4;

    STAGE(0, 0);
    __syncthreads();

    for (int t = 0; t < 9; ++t) {
        const int cur = t & 1;
        if (t < 8) STAGE(cur ^ 1, t + 1);            // prefetch (drained at barrier)
        const char* Kb = smem + cur * 8192;
        const char* Vb = smem + 16384 + cur * 8192;

        // S^T[64 kk][32 q], C-init = -m0 (softmax shift folded into MFMA)
        f32x4 st[2][4];
#pragma unroll
        for (int kb = 0; kb < 4; ++kb) {
            const char* krow = Kb + (kb * 16 + lr) * 128;
            bfrag ka0 = *(const bfrag*)(krow + sw0);
            bfrag ka1 = *(const bfrag*)(krow + sw1);
            f32x4 z0 = (f32x4){-m0[0], -m0[0], -m0[0], -m0[0]};
            z0 = MFMA(ka0, qb[0][0], z0, 0, 0, 0);
            st[0][kb] = MFMA(ka1, qb[0][1], z0, 0, 0, 0);
            f32x4 z1 = (f32x4){-m0[1], -m0[1], -m0[1], -m0[1]};
            z1 = MFMA(ka0, qb[1][0], z1, 0, 0, 0);
            st[1][kb] = MFMA(ka1, qb[1][1], z1, 0, 0, 0);
        }

        // p = 2^s' (shift already applied); no reductions needed
#pragma unroll
        for (int qc = 0; qc < 2; ++qc) {
            char* prow = Pw + (qc * 16 + lr) * 128;
#pragma unroll
            for (int kb = 0; kb < 4; ++kb) {
                float p0 = exp2f(st[qc][kb][0]);
                float p1 = exp2f(st[qc][kb][1]);
                float p2 = exp2f(st[qc][kb][2]);
                float p3 = exp2f(st[qc][kb][3]);
                uint2 u; u.x = cvtpk(p0, p1); u.y = cvtpk(p2, p3);
                int slot = (2 * kb + (lg >> 1)) ^ (lr & 7);
                *(uint2*)(prow + slot * 16 + (lg & 1) * 8) = u;
            }
        }

        // PV: O^T[d][q] += V^T * P^T ; l via ones row
        bfrag pb[2][2];
#pragma unroll
        for (int qc = 0; qc < 2; ++qc) {
            const char* prow = Pw + (qc * 16 + lr) * 128;
            pb[qc][0] = *(const bfrag*)(prow + sw0);
            pb[qc][1] = *(const bfrag*)(prow + sw1);
        }
#pragma unroll
        for (int db = 0; db < 4; ++db) {
            const char* vrow = Vb + (db * 16 + lr) * 128;
            bfrag va0 = *(const bfrag*)(vrow + sw0);
            bfrag va1 = *(const bfrag*)(vrow + sw1);
            o[0][db] = MFMA(va0, pb[0][0], o[0][db], 0, 0, 0);
            o[0][db] = MFMA(va1, pb[0][1], o[0][db], 0, 0, 0);
            o[1][db] = MFMA(va0, pb[1][0], o[1][db], 0, 0, 0);
            o[1][db] = MFMA(va1, pb[1][1], o[1][db], 0, 0, 0);
        }
        o4[0] = MFMA(ones_f, pb[0][0], o4[0], 0, 0, 0);
        o4[0] = MFMA(ones_f, pb[0][1], o4[0], 0, 0, 0);
        o4[1] = MFMA(ones_f, pb[1][0], o4[1], 0, 0, 0);
        o4[1] = MFMA(ones_f, pb[1][1], o4[1], 0, 0, 0);

        __syncthreads();   // drains prefetch vmcnt + protects buffers
    }
#undef STAGE

    // epilogue: pack O' bf16, transpose via LDS, coalesced uint4 stores
    if (lg == 0) {
#pragma unroll
        for (int qc = 0; qc < 2; ++qc)
            Larr[(size_t)(sp * 16 + bh) * NN + n0 + wv * 32 + qc * 16 + lr] = o4[qc][0];
    }
    unsigned (*Osb)[36] = (unsigned(*)[36])smem;   // [128][36] u32 (pitch 36)
#pragma unroll
    for (int qc = 0; qc < 2; ++qc) {
        int row = wv * 32 + qc * 16 + lr;
#pragma unroll
        for (int db = 0; db < 4; ++db) {
            Osb[row][db * 8 + lg * 2 + 0] = cvtpk(o[qc][db][0], o[qc][db][1]);
            Osb[row][db * 8 + lg * 2 + 1] = cvtpk(o[qc][db][2], o[qc][db][3]);
        }
    }
    __syncthreads();
    ushort_t* opb = Op + (size_t)sp * BCN + ((size_t)b * NN + n0) * CCH + h * HD;
    for (int idx = tid; idx < 1024; idx += 256) {
        int n = idx >> 3, s4 = idx & 7;
        *(uint4*)&opb[(size_t)n * CCH + s4 * 8] = *(const uint4*)&Osb[n][s4 * 4];
    }
}

// ---------------------------------------------------------------------------
// fuse: sum kv-splits (bf16 O', shared m0) + depthwise 3x3 BN -> bf16 [b][n][c]
// ---------------------------------------------------------------------------
__global__ __launch_bounds__(256)
void fuse_kernel(const ushort_t* __restrict__ Op, const float* __restrict__ Larr,
                 const ushort_t* __restrict__ Qnd,
                 const ushort_t* __restrict__ pw2, const float* __restrict__ pbias,
                 ushort_t* __restrict__ yt)
{
    const int tid = threadIdx.x;
    const int b  = blockIdx.x / 288;
    const int n0 = (blockIdx.x % 288) * 8;
    const int c8 = tid & 31, ns = tid >> 5;
    const int n  = n0 + ns;
    const int h  = c8 >> 3, c0 = c8 * 8;

    const ushort_t* o0p = Op + ((size_t)b * NN + n) * CCH + c0;
    float acc[8] = {0.f, 0.f, 0.f, 0.f, 0.f, 0.f, 0.f, 0.f};
#pragma unroll
    for (int s = 0; s < NSP; ++s) {
        uint4 u = *(const uint4*)&o0p[(size_t)s * BCN];
        acc[0] += bflo(u.x); acc[1] += bfhi(u.x);
        acc[2] += bflo(u.y); acc[3] += bfhi(u.y);
        acc[4] += bflo(u.z); acc[5] += bfhi(u.z);
        acc[6] += bflo(u.w); acc[7] += bfhi(u.w);
    }
    int mi = (b * HEADS + h) * NN + n;
    float ls = 0.f;
#pragma unroll
    for (int s = 0; s < NSP; ++s) ls += Larr[(size_t)s * 16 * NN + mi];
    float rinv = 1.0f / ls;
#pragma unroll
    for (int j = 0; j < 8; ++j) acc[j] *= rinv;

    const int x = n % WW, y = n / WW;
    const ushort_t* qb = Qnd + (size_t)(b * HEADS + h) * NN * HD + (c8 & 7) * 8;
#pragma unroll
    for (int ky = 0; ky < 3; ++ky) {
        int yy = y + ky - 1;
        if (yy < 0 || yy >= HH) continue;
#pragma unroll
        for (int kx = 0; kx < 3; ++kx) {
            int xx = x + kx - 1;
            if (xx < 0 || xx >= WW) continue;
            int np = yy * WW + xx;
            uint4 qv = *(const uint4*)&qb[(size_t)np * HD];
            uint4 w4 = *(const uint4*)&pw2[(ky * 3 + kx) * CCH + c0];
            acc[0] += bflo(qv.x) * bflo(w4.x); acc[1] += bfhi(qv.x) * bfhi(w4.x);
            acc[2] += bflo(qv.y) * bflo(w4.y); acc[3] += bfhi(qv.y) * bfhi(w4.y);
            acc[4] += bflo(qv.z) * bflo(w4.z); acc[5] += bfhi(qv.z) * bfhi(w4.z);
            acc[6] += bflo(qv.w) * bflo(w4.w); acc[7] += bfhi(qv.w) * bfhi(w4.w);
        }
    }
    float4 p0 = *(const float4*)&pbias[c0];
    float4 p1 = *(const float4*)&pbias[c0 + 4];
    acc[0] += p0.x; acc[1] += p0.y; acc[2] += p0.z; acc[3] += p0.w;
    acc[4] += p1.x; acc[5] += p1.y; acc[6] += p1.z; acc[7] += p1.w;
    uint4 u;
    u.x = cvtpk(acc[0], acc[1]); u.y = cvtpk(acc[2], acc[3]);
    u.z = cvtpk(acc[4], acc[5]); u.w = cvtpk(acc[6], acc[7]);
    *(uint4*)&yt[((size_t)b * NN + n) * CCH + c0] = u;
}

// ---------------------------------------------------------------------------
extern "C" void kernel_launch(void* const* d_in, const int* in_sizes, int n_in,
                              void* d_out, int out_size, void* d_ws, size_t ws_size,
                              hipStream_t stream) {
    const float* q = (const float*)d_in[0];
    const float* k = (const float*)d_in[1];
    const float* v = (const float*)d_in[2];

    char* ws = (char*)d_ws;
    ushort_t* qnd  = (ushort_t*)(ws + 0);
    ushort_t* knd  = (ushort_t*)(ws + 4718592);
    ushort_t* vcn  = (ushort_t*)(ws + 9437184);
    ushort_t* Xt   = (ushort_t*)(ws + 14155776);
    ushort_t* Op   = (ushort_t*)(ws + 14155776);   // bf16 [4][BCN], overlays Xt
    ushort_t* yt   = (ushort_t*)(ws + 4718592);    // overlays knd after attn
    float*    Larr = (float*)   (ws + 33030144);   // [4][16][NN] fp32
    ushort_t* W4   = (ushort_t*)(ws + 33619968);
    float*    bias4= (float*)   (ws + 34144256);
    ushort_t* pw2  = (ushort_t*)(ws + 34148352);
    float*    pbias= (float*)   (ws + 34152960);
    float*    kmax = (float*)   (ws + 34156032);

    prep_transpose<<<3456, 256, 0, stream>>>(q, k, v, Xt);

    PrepWP P;
    P.W[0] = (const float*)d_in[3]; P.W[1] = (const float*)d_in[4];
    P.W[2] = (const float*)d_in[5]; P.W[3] = (const float*)d_in[6];
    P.G[0]  = (const float*)d_in[8];  P.Bb[0] = (const float*)d_in[9];
    P.Mm[0] = (const float*)d_in[10]; P.Vv[0] = (const float*)d_in[11];
    P.G[1]  = (const float*)d_in[12]; P.Bb[1] = (const float*)d_in[13];
    P.Mm[1] = (const float*)d_in[14]; P.Vv[1] = (const float*)d_in[15];
    P.G[2]  = (const float*)d_in[16]; P.Bb[2] = (const float*)d_in[17];
    P.Mm[2] = (const float*)d_in[18]; P.Vv[2] = (const float*)d_in[19];
    P.G[3]  = (const float*)d_in[24]; P.Bb[3] = (const float*)d_in[25];
    P.Mm[3] = (const float*)d_in[26]; P.Vv[3] = (const float*)d_in[27];
    P.pew = (const float*)d_in[7];
    P.peg = (const float*)d_in[20]; P.peb = (const float*)d_in[21];
    P.pem = (const float*)d_in[22]; P.pev = (const float*)d_in[23];
    P.W4 = W4; P.bias4 = bias4; P.pw2 = pw2; P.pbias = pbias;
    prep_w<<<129, 256, 0, stream>>>(P);

    conv_gemm<0><<<dim3(36, 4, 12), 256, 0, stream>>>(Xt, W4, bias4, qnd, knd, vcn, nullptr);

    knorm_kernel<<<16, 256, 0, stream>>>(knd, kmax);

    attn_kernel<<<dim3(18, 16, NSP), 256, 0, stream>>>(qnd, knd, vcn, kmax, Op, Larr);

    fuse_kernel<<<1152, 256, 0, stream>>>(Op, Larr, qnd, pw2, pbias, yt);

    conv_gemm<1><<<dim3(36, 4, 4), 256, 0, stream>>>(yt, W4, bias4, nullptr, nullptr, nullptr,
                                                     (float*)d_out);
}

// Round 8
// 93.766 us; speedup vs baseline: 10.3925x; 1.0556x over previous
//
#include <hip/hip_runtime.h>
#include <math.h>

#define HEADS 4
#define HD    64
#define CCH   256
#define NB    4
#define HH    48
#define WW    48
#define NN    (HH*WW)            // 2304
#define EPSBN 1e-5f
#define KSCL  0.18033688f        // 0.125 * log2(e)  (folded into K weights/bias)
#define BCN   (NB*CCH*NN)        // 2,359,296 elements
#define NSP   4                  // kv splits

typedef unsigned short ushort_t;
typedef __attribute__((ext_vector_type(8))) short bfrag;   // 8 bf16 = 4 VGPR
typedef __attribute__((ext_vector_type(4))) float f32x4;   // MFMA C/D

#define MFMA __builtin_amdgcn_mfma_f32_16x16x32_bf16

static __device__ __forceinline__ ushort_t f2bf(float x) {
    unsigned int u = __float_as_uint(x);
    unsigned int r = (u + 0x7fffu + ((u >> 16) & 1u)) >> 16;   // RNE
    return (ushort_t)r;
}
static __device__ __forceinline__ unsigned cvtpk(float lo, float hi) {
    unsigned r;
    asm("v_cvt_pk_bf16_f32 %0, %1, %2" : "=v"(r) : "v"(lo), "v"(hi));
    return r;
}
static __device__ __forceinline__ float bflo(unsigned u) { return __uint_as_float(u << 16); }
static __device__ __forceinline__ float bfhi(unsigned u) { return __uint_as_float(u & 0xffff0000u); }

static __device__ __forceinline__ void gload16(const void* g, void* l) {
    __builtin_amdgcn_global_load_lds(
        (const __attribute__((address_space(1))) void*)g,
        (__attribute__((address_space(3))) void*)l, 16, 0, 0);
}

// ---------------------------------------------------------------------------
// prep: fp32 [b][c][n] -> bf16 [b][n][c] for q,k,v (register transpose)
// ---------------------------------------------------------------------------
__global__ __launch_bounds__(256)
void prep_transpose(const float* __restrict__ q, const float* __restrict__ k,
                    const float* __restrict__ v, ushort_t* __restrict__ Xt)
{
    const int blk = blockIdx.x;
    const int t  = blk / 1152;
    const int r  = blk % 1152;
    const int b  = r / 288;
    const int r2 = r % 288;
    const int n0 = (r2 >> 3) * 64;
    const int cb = (r2 & 7) * 32;
    const float* X = (t == 0) ? q : (t == 1) ? k : v;
    ushort_t* O = Xt + (size_t)t * BCN;
    const int lane = threadIdx.x & 63;
    const int c0   = cb + (threadIdx.x >> 6) * 8;
    const float* src = X + ((size_t)(b * CCH + c0) * NN + n0 + lane);
    float vv[8];
#pragma unroll
    for (int j = 0; j < 8; ++j) vv[j] = src[(size_t)j * NN];
    uint4 u;
    u.x = cvtpk(vv[0], vv[1]); u.y = cvtpk(vv[2], vv[3]);
    u.z = cvtpk(vv[4], vv[5]); u.w = cvtpk(vv[6], vv[7]);
    *(uint4*)&O[((size_t)b * NN + n0 + lane) * CCH + c0] = u;
}

// ---------------------------------------------------------------------------
// prep: fold BN into weights -> bf16 W'[4][256][256]; bias'[4][256] fp32.
// Also zero-inits kmax2[16].
// ---------------------------------------------------------------------------
struct PrepWP {
    const float* W[4];
    const float* G[4]; const float* Bb[4]; const float* Mm[4]; const float* Vv[4];
    const float* pew; const float* peg; const float* peb; const float* pem; const float* pev;
    ushort_t* W4; float* bias4; ushort_t* pw2; float* pbias; float* kmax2;
};
__global__ __launch_bounds__(256)
void prep_w(PrepWP P)
{
    const int blk = blockIdx.x, tid = threadIdx.x;
    if (blk == 128) {
        int c = tid;
        float s = P.peg[c] * rsqrtf(P.pev[c] + EPSBN);
        for (int tap = 0; tap < 9; ++tap)
            P.pw2[tap * CCH + c] = f2bf(P.pew[c * 9 + tap] * s);
        P.pbias[c] = P.peb[c] - P.pem[c] * s;
        if (tid < 16) P.kmax2[tid] = 0.f;
        return;
    }
    int g  = blk * 256 + tid;
    int cv = g >> 13;
    int o  = (g >> 5) & 255;
    int c8 = g & 31;
    float s  = P.G[cv][o] * rsqrtf(P.Vv[cv][o] + EPSBN);
    float s2 = (cv == 1) ? s * KSCL : s;
    const float* w = P.W[cv] + (size_t)o * CCH + c8 * 8;
    uint4 u;
    u.x = cvtpk(w[0]*s2, w[1]*s2); u.y = cvtpk(w[2]*s2, w[3]*s2);
    u.z = cvtpk(w[4]*s2, w[5]*s2); u.w = cvtpk(w[6]*s2, w[7]*s2);
    *(uint4*)&P.W4[((size_t)cv * CCH + o) * CCH + c8 * 8] = u;
    if (c8 == 0) {
        float bb = (P.Bb[cv][o] - P.Mm[cv][o] * s);
        P.bias4[cv * CCH + o] = (cv == 1) ? bb * KSCL : bb;
    }
}

// ---------------------------------------------------------------------------
// bf16 MFMA 1x1-conv GEMM, 64x64 tile, full K=256 staged once.
// PROJ==0: z = which*4+b, which 0(q),1(k) -> bf16 [b][h][n][d]; 2(v) -> bf16 [b][c][n]
//          which==1 additionally accumulates per-head max row-norm^2 (atomicMax).
// PROJ==1: which=3, fp32 [b][c][n] -> d_out
// ---------------------------------------------------------------------------
template<int PROJ>
__global__ __launch_bounds__(256)
void conv_gemm(const ushort_t* __restrict__ T, const ushort_t* __restrict__ W4,
               const float* __restrict__ bias4,
               ushort_t* __restrict__ qnd, ushort_t* __restrict__ knd,
               ushort_t* __restrict__ vcn, float* __restrict__ outf,
               float* __restrict__ kmax2)
{
    __shared__ ushort_t Ts[64][264];
    __shared__ ushort_t Ws[64][264];
    const int nt = blockIdx.x, ot = blockIdx.y, z = blockIdx.z;
    const int which = PROJ ? 3 : (z >> 2);
    const int b = z & 3;
    const int tid = threadIdx.x;
    const int n0 = nt * 64, o0 = ot * 64;
    const ushort_t* Tsrc = T + (PROJ ? (size_t)0 : (size_t)which * BCN) + ((size_t)b * NN + n0) * CCH;
    const ushort_t* Wsrc = W4 + (size_t)which * CCH * CCH + (size_t)o0 * CCH;
    const float*    bias = bias4 + which * CCH;
#pragma unroll
    for (int i = 0; i < 8; ++i) {
        int idx = tid + i * 256;
        int r = idx >> 5, c16 = idx & 31;
        *(uint4*)&Ts[r][c16 * 8] = *(const uint4*)&Tsrc[(size_t)r * CCH + c16 * 8];
        *(uint4*)&Ws[r][c16 * 8] = *(const uint4*)&Wsrc[(size_t)r * CCH + c16 * 8];
    }
    __syncthreads();
    const int wv = tid >> 6, lane = tid & 63, lr = lane & 15, lg = lane >> 4;
    const int qn = (wv >> 1) * 32, qo = (wv & 1) * 32;
    f32x4 acc[2][2];
#pragma unroll
    for (int i = 0; i < 2; ++i)
#pragma unroll
        for (int j = 0; j < 2; ++j) acc[i][j] = (f32x4){0.f, 0.f, 0.f, 0.f};

    if (!PROJ && (z >> 2) < 2) {
#pragma unroll
        for (int k8 = 0; k8 < 8; ++k8) {
            const int kc = k8 * 32 + lg * 8;
            bfrag ta0 = *(const bfrag*)&Ts[qn + lr][kc];
            bfrag ta1 = *(const bfrag*)&Ts[qn + 16 + lr][kc];
            bfrag wa0 = *(const bfrag*)&Ws[qo + lr][kc];
            bfrag wa1 = *(const bfrag*)&Ws[qo + 16 + lr][kc];
            acc[0][0] = MFMA(ta0, wa0, acc[0][0], 0, 0, 0);
            acc[0][1] = MFMA(ta0, wa1, acc[0][1], 0, 0, 0);
            acc[1][0] = MFMA(ta1, wa0, acc[1][0], 0, 0, 0);
            acc[1][1] = MFMA(ta1, wa1, acc[1][1], 0, 0, 0);
        }
    } else {
#pragma unroll
        for (int k8 = 0; k8 < 8; ++k8) {
            const int kc = k8 * 32 + lg * 8;
            bfrag ta0 = *(const bfrag*)&Ts[qn + lr][kc];
            bfrag ta1 = *(const bfrag*)&Ts[qn + 16 + lr][kc];
            bfrag wa0 = *(const bfrag*)&Ws[qo + lr][kc];
            bfrag wa1 = *(const bfrag*)&Ws[qo + 16 + lr][kc];
            acc[0][0] = MFMA(wa0, ta0, acc[0][0], 0, 0, 0);
            acc[0][1] = MFMA(wa0, ta1, acc[0][1], 0, 0, 0);
            acc[1][0] = MFMA(wa1, ta0, acc[1][0], 0, 0, 0);
            acc[1][1] = MFMA(wa1, ta1, acc[1][1], 0, 0, 0);
        }
    }

    __syncthreads();   // Ts/Ws dead; overlay epilogue staging
    if (!PROJ && which < 2) {
        ushort_t (*Ot)[72] = (ushort_t(*)[72])Ts;
        float bv[2] = { bias[o0 + qo + lr], bias[o0 + qo + 16 + lr] };
#pragma unroll
        for (int i = 0; i < 2; ++i)
#pragma unroll
            for (int j = 0; j < 2; ++j)
#pragma unroll
                for (int r = 0; r < 4; ++r)
                    Ot[qn + i * 16 + lg * 4 + r][qo + j * 16 + lr] = f2bf(acc[i][j][r] + bv[j]);
        __syncthreads();
        ushort_t* out = (which == 0) ? qnd : knd;
        for (int idx = tid; idx < 512; idx += 256) {
            int r = idx >> 3, sg = idx & 7;
            *(uint4*)&out[(((size_t)b * HEADS + ot) * NN + n0 + r) * HD + sg * 8] =
                *(const uint4*)&Ot[r][sg * 8];
        }
        if (which == 1 && tid < 64) {   // per-head max row-norm^2 of K'
            float s = 0.f;
#pragma unroll
            for (int j = 0; j < 8; ++j) {
                uint4 u = *(const uint4*)&Ot[tid][j * 8];
                s += bflo(u.x)*bflo(u.x) + bfhi(u.x)*bfhi(u.x);
                s += bflo(u.y)*bflo(u.y) + bfhi(u.y)*bfhi(u.y);
                s += bflo(u.z)*bflo(u.z) + bfhi(u.z)*bfhi(u.z);
                s += bflo(u.w)*bflo(u.w) + bfhi(u.w)*bfhi(u.w);
            }
            atomicMax((unsigned*)&kmax2[b * HEADS + ot], __float_as_uint(s));
        }
    } else if (!PROJ) {
        ushort_t (*Ot)[72] = (ushort_t(*)[72])Ts;
#pragma unroll
        for (int i = 0; i < 2; ++i)
#pragma unroll
            for (int r = 0; r < 4; ++r) {
                float bv = bias[o0 + qo + i * 16 + lg * 4 + r];
#pragma unroll
                for (int j = 0; j < 2; ++j)
                    Ot[qo + i * 16 + lg * 4 + r][qn + j * 16 + lr] = f2bf(acc[i][j][r] + bv);
            }
        __syncthreads();
        for (int idx = tid; idx < 512; idx += 256) {
            int r = idx >> 3, sg = idx & 7;
            *(uint4*)&vcn[((size_t)b * CCH + o0 + r) * NN + n0 + sg * 8] =
                *(const uint4*)&Ot[r][sg * 8];
        }
    } else {
        float (*Of)[68] = (float(*)[68])Ts;
#pragma unroll
        for (int i = 0; i < 2; ++i)
#pragma unroll
            for (int r = 0; r < 4; ++r) {
                float bv = bias[o0 + qo + i * 16 + lg * 4 + r];
#pragma unroll
                for (int j = 0; j < 2; ++j)
                    Of[qo + i * 16 + lg * 4 + r][qn + j * 16 + lr] = acc[i][j][r] + bv;
            }
        __syncthreads();
        for (int idx = tid; idx < 1024; idx += 256) {
            int r = idx >> 4, c4 = idx & 15;
            *(float4*)&outf[((size_t)b * CCH + o0 + r) * NN + n0 + c4 * 4] =
                *(const float4*)&Of[r][c4 * 4];
        }
    }
}

// ---------------------------------------------------------------------------
// MFMA flash attention: 4 waves x 32 q = 128 q rows/block, Bc=64, kv-split x4.
// Norm-bound fixed softmax max folded into MFMA C-init; l via ones-row MFMA.
// Per-qc P staging reuses a 2KB/wave LDS region -> 40KB total -> 4 blocks/CU.
// ---------------------------------------------------------------------------
__global__ __launch_bounds__(256, 4)
void attn_kernel(const ushort_t* __restrict__ Qnd,   // bf16 [b][h][n][d]
                 const ushort_t* __restrict__ Knd,   // bf16 [b][h][n][d] *KSCL
                 const ushort_t* __restrict__ Vcn,   // bf16 [b][c][n]
                 const float* __restrict__ kmax2,    // [16] max row-norm^2
                 ushort_t* __restrict__ Op,          // bf16 [4][b][n][c]
                 float* __restrict__ Larr)           // fp32 [4][16][NN]
{
    __shared__ __align__(16) char smem[40960];
    // K2 @0: [2][64][64]sw ; V2 @16384: [2][64][64]sw ; Ps @32768: [4][16][64]sw

    const int tid = threadIdx.x;
    const int lin0 = blockIdx.x + 18 * blockIdx.y + 288 * blockIdx.z;
    const int w    = (lin0 & 7) * 144 + (lin0 >> 3);   // XCD-chunked remap (1152=8*144)
    const int qt = w % 18;
    const int bh = (w / 18) & 15;
    const int sp = w / 288;
    const int b = bh >> 2, h = bh & 3;
    const int lane = tid & 63, wv = tid >> 6;
    const int lr = lane & 15, lg = lane >> 4;
    const int lrow = lane >> 3, lslot = (lane & 7) ^ lrow;
    const int n0 = qt * 128;
    const size_t ndb = (size_t)(b * HEADS + h) * NN * HD;
    const size_t cnb = ((size_t)b * CCH + h * HD) * NN;

    // staging pointers (pre-swizzled global source, linear LDS dest)
    const char* kgp = (const char*)(Knd + ndb) + (size_t)(sp * 576 + wv * 16 + lrow) * 128 + lslot * 16;
    const char* vgp = (const char*)(Vcn + cnb + sp * 576) + (size_t)(wv * 16 + lrow) * (NN * 2) + lslot * 16;
    char* kls = smem + wv * 2048;
    char* vls = smem + 16384 + wv * 2048;

#define STAGE(buf, t) do { \
    const char* kp_ = kgp + (size_t)(t) * 8192; \
    const char* vp_ = vgp + (size_t)(t) * 128; \
    char* kd_ = kls + (buf) * 8192; \
    char* vd_ = vls + (buf) * 8192; \
    gload16(kp_,               kd_); \
    gload16(kp_ + 1024,        kd_ + 1024); \
    gload16(vp_,               vd_); \
    gload16(vp_ + 8 * (NN*2),  vd_ + 1024); \
} while (0)

    // Q fragments (32 q rows per wave)
    bfrag qb[2][2];
    {
        const ushort_t* qbase = Qnd + ndb + (size_t)(n0 + wv * 32 + lr) * HD;
        qb[0][0] = *(const bfrag*)&qbase[lg * 8];
        qb[0][1] = *(const bfrag*)&qbase[32 + lg * 8];
        qb[1][0] = *(const bfrag*)&qbase[16 * HD + lg * 8];
        qb[1][1] = *(const bfrag*)&qbase[16 * HD + 32 + lg * 8];
    }
    // fixed softmax bound m0 = |q| * max|k'| + margin
    float m0[2];
    {
        const float kmx = sqrtf(kmax2[bh]);
#pragma unroll
        for (int qc = 0; qc < 2; ++qc) {
            const unsigned* u0 = (const unsigned*)&qb[qc][0];
            const unsigned* u1 = (const unsigned*)&qb[qc][1];
            float s = 0.f;
#pragma unroll
            for (int j = 0; j < 4; ++j) {
                float a0 = bflo(u0[j]), a1 = bfhi(u0[j]);
                float b0 = bflo(u1[j]), b1 = bfhi(u1[j]);
                s += a0*a0 + a1*a1 + b0*b0 + b1*b1;
            }
            s += __shfl_xor(s, 16);
            s += __shfl_xor(s, 32);
            m0[qc] = sqrtf(s) * kmx + 0.5f;
        }
    }
    // ones A-fragment (row 0 = 1.0, rows 1..15 = 0) for l accumulation
    bfrag ones_f;
    {
        short ov = (lr == 0) ? (short)0x3F80 : (short)0;
#pragma unroll
        for (int j = 0; j < 8; ++j) ones_f[j] = ov;
    }

    f32x4 o[2][4], o4[2];
#pragma unroll
    for (int qc = 0; qc < 2; ++qc) {
        o4[qc] = (f32x4){0.f, 0.f, 0.f, 0.f};
#pragma unroll
        for (int db = 0; db < 4; ++db) o[qc][db] = (f32x4){0.f, 0.f, 0.f, 0.f};
    }

    char* Pw = smem + 32768 + wv * 2048;   // wave's P: [16 q][64 kk] swizzled (reused per qc)
    const int sw0 = (lg ^ (lr & 7)) << 4;
    const int sw1 = ((4 + lg) ^ (lr & 7)) << 4;

    STAGE(0, 0);
    __syncthreads();

    for (int t = 0; t < 9; ++t) {
        const int cur = t & 1;
        if (t < 8) STAGE(cur ^ 1, t + 1);            // prefetch (drained at barrier)
        const char* Kb = smem + cur * 8192;
        const char* Vb = smem + 16384 + cur * 8192;

        // S^T[64 kk][32 q], C-init = -m0 (softmax shift folded into MFMA)
        f32x4 st[2][4];
#pragma unroll
        for (int kb = 0; kb < 4; ++kb) {
            const char* krow = Kb + (kb * 16 + lr) * 128;
            bfrag ka0 = *(const bfrag*)(krow + sw0);
            bfrag ka1 = *(const bfrag*)(krow + sw1);
            f32x4 z0 = (f32x4){-m0[0], -m0[0], -m0[0], -m0[0]};
            z0 = MFMA(ka0, qb[0][0], z0, 0, 0, 0);
            st[0][kb] = MFMA(ka1, qb[0][1], z0, 0, 0, 0);
            f32x4 z1 = (f32x4){-m0[1], -m0[1], -m0[1], -m0[1]};
            z1 = MFMA(ka0, qb[1][0], z1, 0, 0, 0);
            st[1][kb] = MFMA(ka1, qb[1][1], z1, 0, 0, 0);
        }

        // per-qc: p = 2^s' -> pack bf16 -> LDS (2KB region reused) -> B-fragments
        bfrag pb[2][2];
#pragma unroll
        for (int qc = 0; qc < 2; ++qc) {
            char* prow = Pw + lr * 128;
#pragma unroll
            for (int kb = 0; kb < 4; ++kb) {
                float p0 = exp2f(st[qc][kb][0]);
                float p1 = exp2f(st[qc][kb][1]);
                float p2 = exp2f(st[qc][kb][2]);
                float p3 = exp2f(st[qc][kb][3]);
                uint2 u; u.x = cvtpk(p0, p1); u.y = cvtpk(p2, p3);
                int slot = (2 * kb + (lg >> 1)) ^ (lr & 7);
                *(uint2*)(prow + slot * 16 + (lg & 1) * 8) = u;
            }
            pb[qc][0] = *(const bfrag*)(prow + sw0);
            pb[qc][1] = *(const bfrag*)(prow + sw1);
        }

        // PV: O^T[d][q] += V^T * P^T ; l via ones row
#pragma unroll
        for (int db = 0; db < 4; ++db) {
            const char* vrow = Vb + (db * 16 + lr) * 128;
            bfrag va0 = *(const bfrag*)(vrow + sw0);
            bfrag va1 = *(const bfrag*)(vrow + sw1);
            o[0][db] = MFMA(va0, pb[0][0], o[0][db], 0, 0, 0);
            o[0][db] = MFMA(va1, pb[0][1], o[0][db], 0, 0, 0);
            o[1][db] = MFMA(va0, pb[1][0], o[1][db], 0, 0, 0);
            o[1][db] = MFMA(va1, pb[1][1], o[1][db], 0, 0, 0);
        }
        o4[0] = MFMA(ones_f, pb[0][0], o4[0], 0, 0, 0);
        o4[0] = MFMA(ones_f, pb[0][1], o4[0], 0, 0, 0);
        o4[1] = MFMA(ones_f, pb[1][0], o4[1], 0, 0, 0);
        o4[1] = MFMA(ones_f, pb[1][1], o4[1], 0, 0, 0);

        __syncthreads();   // drains prefetch vmcnt + protects buffers
    }
#undef STAGE

    // epilogue: pack O' bf16, transpose via LDS, coalesced uint4 stores
    if (lg == 0) {
#pragma unroll
        for (int qc = 0; qc < 2; ++qc)
            Larr[(size_t)(sp * 16 + bh) * NN + n0 + wv * 32 + qc * 16 + lr] = o4[qc][0];
    }
    unsigned (*Osb)[36] = (unsigned(*)[36])smem;   // [128][36] u32 (pitch 36)
#pragma unroll
    for (int qc = 0; qc < 2; ++qc) {
        int row = wv * 32 + qc * 16 + lr;
#pragma unroll
        for (int db = 0; db < 4; ++db) {
            Osb[row][db * 8 + lg * 2 + 0] = cvtpk(o[qc][db][0], o[qc][db][1]);
            Osb[row][db * 8 + lg * 2 + 1] = cvtpk(o[qc][db][2], o[qc][db][3]);
        }
    }
    __syncthreads();
    ushort_t* opb = Op + (size_t)sp * BCN + ((size_t)b * NN + n0) * CCH + h * HD;
    for (int idx = tid; idx < 1024; idx += 256) {
        int n = idx >> 3, s4 = idx & 7;
        *(uint4*)&opb[(size_t)n * CCH + s4 * 8] = *(const uint4*)&Osb[n][s4 * 4];
    }
}

// ---------------------------------------------------------------------------
// fuse: sum kv-splits (bf16 O', shared m0) + depthwise 3x3 BN -> bf16 [b][n][c]
// ---------------------------------------------------------------------------
__global__ __launch_bounds__(256)
void fuse_kernel(const ushort_t* __restrict__ Op, const float* __restrict__ Larr,
                 const ushort_t* __restrict__ Qnd,
                 const ushort_t* __restrict__ pw2, const float* __restrict__ pbias,
                 ushort_t* __restrict__ yt)
{
    const int tid = threadIdx.x;
    const int b  = blockIdx.x / 288;
    const int n0 = (blockIdx.x % 288) * 8;
    const int c8 = tid & 31, ns = tid >> 5;
    const int n  = n0 + ns;
    const int h  = c8 >> 3, c0 = c8 * 8;

    const ushort_t* o0p = Op + ((size_t)b * NN + n) * CCH + c0;
    float acc[8] = {0.f, 0.f, 0.f, 0.f, 0.f, 0.f, 0.f, 0.f};
#pragma unroll
    for (int s = 0; s < NSP; ++s) {
        uint4 u = *(const uint4*)&o0p[(size_t)s * BCN];
        acc[0] += bflo(u.x); acc[1] += bfhi(u.x);
        acc[2] += bflo(u.y); acc[3] += bfhi(u.y);
        acc[4] += bflo(u.z); acc[5] += bfhi(u.z);
        acc[6] += bflo(u.w); acc[7] += bfhi(u.w);
    }
    int mi = (b * HEADS + h) * NN + n;
    float ls = 0.f;
#pragma unroll
    for (int s = 0; s < NSP; ++s) ls += Larr[(size_t)s * 16 * NN + mi];
    float rinv = 1.0f / ls;
#pragma unroll
    for (int j = 0; j < 8; ++j) acc[j] *= rinv;

    const int x = n % WW, y = n / WW;
    const ushort_t* qb = Qnd + (size_t)(b * HEADS + h) * NN * HD + (c8 & 7) * 8;
#pragma unroll
    for (int ky = 0; ky < 3; ++ky) {
        int yy = y + ky - 1;
        if (yy < 0 || yy >= HH) continue;
#pragma unroll
        for (int kx = 0; kx < 3; ++kx) {
            int xx = x + kx - 1;
            if (xx < 0 || xx >= WW) continue;
            int np = yy * WW + xx;
            uint4 qv = *(const uint4*)&qb[(size_t)np * HD];
            uint4 w4 = *(const uint4*)&pw2[(ky * 3 + kx) * CCH + c0];
            acc[0] += bflo(qv.x) * bflo(w4.x); acc[1] += bfhi(qv.x) * bfhi(w4.x);
            acc[2] += bflo(qv.y) * bflo(w4.y); acc[3] += bfhi(qv.y) * bfhi(w4.y);
            acc[4] += bflo(qv.z) * bflo(w4.z); acc[5] += bfhi(qv.z) * bfhi(w4.z);
            acc[6] += bflo(qv.w) * bflo(w4.w); acc[7] += bfhi(qv.w) * bfhi(w4.w);
        }
    }
    float4 p0 = *(const float4*)&pbias[c0];
    float4 p1 = *(const float4*)&pbias[c0 + 4];
    acc[0] += p0.x; acc[1] += p0.y; acc[2] += p0.z; acc[3] += p0.w;
    acc[4] += p1.x; acc[5] += p1.y; acc[6] += p1.z; acc[7] += p1.w;
    uint4 u;
    u.x = cvtpk(acc[0], acc[1]); u.y = cvtpk(acc[2], acc[3]);
    u.z = cvtpk(acc[4], acc[5]); u.w = cvtpk(acc[6], acc[7]);
    *(uint4*)&yt[((size_t)b * NN + n) * CCH + c0] = u;
}

// ---------------------------------------------------------------------------
extern "C" void kernel_launch(void* const* d_in, const int* in_sizes, int n_in,
                              void* d_out, int out_size, void* d_ws, size_t ws_size,
                              hipStream_t stream) {
    const float* q = (const float*)d_in[0];
    const float* k = (const float*)d_in[1];
    const float* v = (const float*)d_in[2];

    char* ws = (char*)d_ws;
    ushort_t* qnd  = (ushort_t*)(ws + 0);
    ushort_t* knd  = (ushort_t*)(ws + 4718592);
    ushort_t* vcn  = (ushort_t*)(ws + 9437184);
    ushort_t* Xt   = (ushort_t*)(ws + 14155776);
    ushort_t* Op   = (ushort_t*)(ws + 14155776);   // bf16 [4][BCN], overlays Xt
    ushort_t* yt   = (ushort_t*)(ws + 4718592);    // overlays knd after attn
    float*    Larr = (float*)   (ws + 33030144);   // [4][16][NN] fp32
    ushort_t* W4   = (ushort_t*)(ws + 33619968);
    float*    bias4= (float*)   (ws + 34144256);
    ushort_t* pw2  = (ushort_t*)(ws + 34148352);
    float*    pbias= (float*)   (ws + 34152960);
    float*    kmax2= (float*)   (ws + 34156032);

    prep_transpose<<<3456, 256, 0, stream>>>(q, k, v, Xt);

    PrepWP P;
    P.W[0] = (const float*)d_in[3]; P.W[1] = (const float*)d_in[4];
    P.W[2] = (const float*)d_in[5]; P.W[3] = (const float*)d_in[6];
    P.G[0]  = (const float*)d_in[8];  P.Bb[0] = (const float*)d_in[9];
    P.Mm[0] = (const float*)d_in[10]; P.Vv[0] = (const float*)d_in[11];
    P.G[1]  = (const float*)d_in[12]; P.Bb[1] = (const float*)d_in[13];
    P.Mm[1] = (const float*)d_in[14]; P.Vv[1] = (const float*)d_in[15];
    P.G[2]  = (const float*)d_in[16]; P.Bb[2] = (const float*)d_in[17];
    P.Mm[2] = (const float*)d_in[18]; P.Vv[2] = (const float*)d_in[19];
    P.G[3]  = (const float*)d_in[24]; P.Bb[3] = (const float*)d_in[25];
    P.Mm[3] = (const float*)d_in[26]; P.Vv[3] = (const float*)d_in[27];
    P.pew = (const float*)d_in[7];
    P.peg = (const float*)d_in[20]; P.peb = (const float*)d_in[21];
    P.pem = (const float*)d_in[22]; P.pev = (const float*)d_in[23];
    P.W4 = W4; P.bias4 = bias4; P.pw2 = pw2; P.pbias = pbias; P.kmax2 = kmax2;
    prep_w<<<129, 256, 0, stream>>>(P);

    conv_gemm<0><<<dim3(36, 4, 12), 256, 0, stream>>>(Xt, W4, bias4, qnd, knd, vcn, nullptr, kmax2);

    attn_kernel<<<dim3(18, 16, NSP), 256, 0, stream>>>(qnd, knd, vcn, kmax2, Op, Larr);

    fuse_kernel<<<1152, 256, 0, stream>>>(Op, Larr, qnd, pw2, pbias, yt);

    conv_gemm<1><<<dim3(36, 4, 4), 256, 0, stream>>>(yt, W4, bias4, nullptr, nullptr, nullptr,
                                                     (float*)d_out, nullptr);
}

// Round 9
// 93.639 us; speedup vs baseline: 10.4066x; 1.0014x over previous
//
#include <hip/hip_runtime.h>
#include <math.h>

#define HEADS 4
#define HD    64
#define CCH   256
#define NB    4
#define HH    48
#define WW    48
#define NN    (HH*WW)            // 2304
#define EPSBN 1e-5f
#define KSCL  0.18033688f        // 0.125 * log2(e)  (folded into K weights/bias)
#define BCN   (NB*CCH*NN)        // 2,359,296 elements
#define NSP   4                  // kv splits

typedef unsigned short ushort_t;
typedef __attribute__((ext_vector_type(8))) short bfrag;   // 8 bf16 = 4 VGPR
typedef __attribute__((ext_vector_type(4))) float f32x4;   // MFMA C/D

#define MFMA __builtin_amdgcn_mfma_f32_16x16x32_bf16

static __device__ __forceinline__ ushort_t f2bf(float x) {
    unsigned int u = __float_as_uint(x);
    unsigned int r = (u + 0x7fffu + ((u >> 16) & 1u)) >> 16;   // RNE
    return (ushort_t)r;
}
static __device__ __forceinline__ unsigned cvtpk(float lo, float hi) {
    unsigned r;
    asm("v_cvt_pk_bf16_f32 %0, %1, %2" : "=v"(r) : "v"(lo), "v"(hi));
    return r;
}
static __device__ __forceinline__ float bflo(unsigned u) { return __uint_as_float(u << 16); }
static __device__ __forceinline__ float bfhi(unsigned u) { return __uint_as_float(u & 0xffff0000u); }

static __device__ __forceinline__ void gload16(const void* g, void* l) {
    __builtin_amdgcn_global_load_lds(
        (const __attribute__((address_space(1))) void*)g,
        (__attribute__((address_space(3))) void*)l, 16, 0, 0);
}

// ---------------------------------------------------------------------------
// prep (merged): blocks < 3456: fp32 [b][c][n] -> bf16 [b][n][c] for q,k,v.
// blocks >= 3456: fold BN into weights -> bf16 W'[4][256][256], bias'[4][256];
// pe weights tap-major bf16; kmax2 zero-init.
// ---------------------------------------------------------------------------
struct PrepWP {
    const float* W[4];
    const float* G[4]; const float* Bb[4]; const float* Mm[4]; const float* Vv[4];
    const float* pew; const float* peg; const float* peb; const float* pem; const float* pev;
    ushort_t* W4; float* bias4; ushort_t* pw2; float* pbias; float* kmax2;
    const float* q; const float* k; const float* v; ushort_t* Xt;
};
__global__ __launch_bounds__(256)
void prep_kernel(PrepWP P)
{
    const int blk = blockIdx.x, tid = threadIdx.x;
    if (blk < 3456) {            // transpose path
        const int t  = blk / 1152;
        const int r  = blk % 1152;
        const int b  = r / 288;
        const int r2 = r % 288;
        const int n0 = (r2 >> 3) * 64;
        const int cb = (r2 & 7) * 32;
        const float* X = (t == 0) ? P.q : (t == 1) ? P.k : P.v;
        ushort_t* O = P.Xt + (size_t)t * BCN;
        const int lane = tid & 63;
        const int c0   = cb + (tid >> 6) * 8;
        const float* src = X + ((size_t)(b * CCH + c0) * NN + n0 + lane);
        float vv[8];
#pragma unroll
        for (int j = 0; j < 8; ++j) vv[j] = src[(size_t)j * NN];
        uint4 u;
        u.x = cvtpk(vv[0], vv[1]); u.y = cvtpk(vv[2], vv[3]);
        u.z = cvtpk(vv[4], vv[5]); u.w = cvtpk(vv[6], vv[7]);
        *(uint4*)&O[((size_t)b * NN + n0 + lane) * CCH + c0] = u;
        return;
    }
    const int wb = blk - 3456;
    if (wb == 128) {
        int c = tid;
        float s = P.peg[c] * rsqrtf(P.pev[c] + EPSBN);
        for (int tap = 0; tap < 9; ++tap)
            P.pw2[tap * CCH + c] = f2bf(P.pew[c * 9 + tap] * s);
        P.pbias[c] = P.peb[c] - P.pem[c] * s;
        if (tid < 16) P.kmax2[tid] = 0.f;
        return;
    }
    int g  = wb * 256 + tid;
    int cv = g >> 13;
    int o  = (g >> 5) & 255;
    int c8 = g & 31;
    float s  = P.G[cv][o] * rsqrtf(P.Vv[cv][o] + EPSBN);
    float s2 = (cv == 1) ? s * KSCL : s;
    const float* w = P.W[cv] + (size_t)o * CCH + c8 * 8;
    uint4 u;
    u.x = cvtpk(w[0]*s2, w[1]*s2); u.y = cvtpk(w[2]*s2, w[3]*s2);
    u.z = cvtpk(w[4]*s2, w[5]*s2); u.w = cvtpk(w[6]*s2, w[7]*s2);
    *(uint4*)&P.W4[((size_t)cv * CCH + o) * CCH + c8 * 8] = u;
    if (c8 == 0) {
        float bb = (P.Bb[cv][o] - P.Mm[cv][o] * s);
        P.bias4[cv * CCH + o] = (cv == 1) ? bb * KSCL : bb;
    }
}

// ---------------------------------------------------------------------------
// bf16 MFMA 1x1-conv GEMM, 64x64 tile, full K=256 staged once.
// PROJ==0: z = which*4+b, which 0(q),1(k) -> bf16 [b][h][n][d]; 2(v) -> bf16 [b][c][n]
//          which==1 additionally accumulates per-head max row-norm^2 (atomicMax).
// PROJ==1: which=3, fp32 [b][c][n] -> d_out
// ---------------------------------------------------------------------------
template<int PROJ>
__global__ __launch_bounds__(256)
void conv_gemm(const ushort_t* __restrict__ T, const ushort_t* __restrict__ W4,
               const float* __restrict__ bias4,
               ushort_t* __restrict__ qnd, ushort_t* __restrict__ knd,
               ushort_t* __restrict__ vcn, float* __restrict__ outf,
               float* __restrict__ kmax2)
{
    __shared__ ushort_t Ts[64][264];
    __shared__ ushort_t Ws[64][264];
    const int nt = blockIdx.x, ot = blockIdx.y, z = blockIdx.z;
    const int which = PROJ ? 3 : (z >> 2);
    const int b = z & 3;
    const int tid = threadIdx.x;
    const int n0 = nt * 64, o0 = ot * 64;
    const ushort_t* Tsrc = T + (PROJ ? (size_t)0 : (size_t)which * BCN) + ((size_t)b * NN + n0) * CCH;
    const ushort_t* Wsrc = W4 + (size_t)which * CCH * CCH + (size_t)o0 * CCH;
    const float*    bias = bias4 + which * CCH;
#pragma unroll
    for (int i = 0; i < 8; ++i) {
        int idx = tid + i * 256;
        int r = idx >> 5, c16 = idx & 31;
        *(uint4*)&Ts[r][c16 * 8] = *(const uint4*)&Tsrc[(size_t)r * CCH + c16 * 8];
        *(uint4*)&Ws[r][c16 * 8] = *(const uint4*)&Wsrc[(size_t)r * CCH + c16 * 8];
    }
    __syncthreads();
    const int wv = tid >> 6, lane = tid & 63, lr = lane & 15, lg = lane >> 4;
    const int qn = (wv >> 1) * 32, qo = (wv & 1) * 32;
    f32x4 acc[2][2];
#pragma unroll
    for (int i = 0; i < 2; ++i)
#pragma unroll
        for (int j = 0; j < 2; ++j) acc[i][j] = (f32x4){0.f, 0.f, 0.f, 0.f};

    if (!PROJ && (z >> 2) < 2) {
#pragma unroll
        for (int k8 = 0; k8 < 8; ++k8) {
            const int kc = k8 * 32 + lg * 8;
            bfrag ta0 = *(const bfrag*)&Ts[qn + lr][kc];
            bfrag ta1 = *(const bfrag*)&Ts[qn + 16 + lr][kc];
            bfrag wa0 = *(const bfrag*)&Ws[qo + lr][kc];
            bfrag wa1 = *(const bfrag*)&Ws[qo + 16 + lr][kc];
            acc[0][0] = MFMA(ta0, wa0, acc[0][0], 0, 0, 0);
            acc[0][1] = MFMA(ta0, wa1, acc[0][1], 0, 0, 0);
            acc[1][0] = MFMA(ta1, wa0, acc[1][0], 0, 0, 0);
            acc[1][1] = MFMA(ta1, wa1, acc[1][1], 0, 0, 0);
        }
    } else {
#pragma unroll
        for (int k8 = 0; k8 < 8; ++k8) {
            const int kc = k8 * 32 + lg * 8;
            bfrag ta0 = *(const bfrag*)&Ts[qn + lr][kc];
            bfrag ta1 = *(const bfrag*)&Ts[qn + 16 + lr][kc];
            bfrag wa0 = *(const bfrag*)&Ws[qo + lr][kc];
            bfrag wa1 = *(const bfrag*)&Ws[qo + 16 + lr][kc];
            acc[0][0] = MFMA(wa0, ta0, acc[0][0], 0, 0, 0);
            acc[0][1] = MFMA(wa0, ta1, acc[0][1], 0, 0, 0);
            acc[1][0] = MFMA(wa1, ta0, acc[1][0], 0, 0, 0);
            acc[1][1] = MFMA(wa1, ta1, acc[1][1], 0, 0, 0);
        }
    }

    __syncthreads();   // Ts/Ws dead; overlay epilogue staging
    if (!PROJ && which < 2) {
        ushort_t (*Ot)[72] = (ushort_t(*)[72])Ts;
        float bv[2] = { bias[o0 + qo + lr], bias[o0 + qo + 16 + lr] };
#pragma unroll
        for (int i = 0; i < 2; ++i)
#pragma unroll
            for (int j = 0; j < 2; ++j)
#pragma unroll
                for (int r = 0; r < 4; ++r)
                    Ot[qn + i * 16 + lg * 4 + r][qo + j * 16 + lr] = f2bf(acc[i][j][r] + bv[j]);
        __syncthreads();
        ushort_t* out = (which == 0) ? qnd : knd;
        for (int idx = tid; idx < 512; idx += 256) {
            int r = idx >> 3, sg = idx & 7;
            *(uint4*)&out[(((size_t)b * HEADS + ot) * NN + n0 + r) * HD + sg * 8] =
                *(const uint4*)&Ot[r][sg * 8];
        }
        if (which == 1 && tid < 64) {   // per-head max row-norm^2 of K'
            float s = 0.f;
#pragma unroll
            for (int j = 0; j < 8; ++j) {
                uint4 u = *(const uint4*)&Ot[tid][j * 8];
                s += bflo(u.x)*bflo(u.x) + bfhi(u.x)*bfhi(u.x);
                s += bflo(u.y)*bflo(u.y) + bfhi(u.y)*bfhi(u.y);
                s += bflo(u.z)*bflo(u.z) + bfhi(u.z)*bfhi(u.z);
                s += bflo(u.w)*bflo(u.w) + bfhi(u.w)*bfhi(u.w);
            }
            atomicMax((unsigned*)&kmax2[b * HEADS + ot], __float_as_uint(s));
        }
    } else if (!PROJ) {
        ushort_t (*Ot)[72] = (ushort_t(*)[72])Ts;
#pragma unroll
        for (int i = 0; i < 2; ++i)
#pragma unroll
            for (int r = 0; r < 4; ++r) {
                float bv = bias[o0 + qo + i * 16 + lg * 4 + r];
#pragma unroll
                for (int j = 0; j < 2; ++j)
                    Ot[qo + i * 16 + lg * 4 + r][qn + j * 16 + lr] = f2bf(acc[i][j][r] + bv);
            }
        __syncthreads();
        for (int idx = tid; idx < 512; idx += 256) {
            int r = idx >> 3, sg = idx & 7;
            *(uint4*)&vcn[((size_t)b * CCH + o0 + r) * NN + n0 + sg * 8] =
                *(const uint4*)&Ot[r][sg * 8];
        }
    } else {
        float (*Of)[68] = (float(*)[68])Ts;
#pragma unroll
        for (int i = 0; i < 2; ++i)
#pragma unroll
            for (int r = 0; r < 4; ++r) {
                float bv = bias[o0 + qo + i * 16 + lg * 4 + r];
#pragma unroll
                for (int j = 0; j < 2; ++j)
                    Of[qo + i * 16 + lg * 4 + r][qn + j * 16 + lr] = acc[i][j][r] + bv;
            }
        __syncthreads();
        for (int idx = tid; idx < 1024; idx += 256) {
            int r = idx >> 4, c4 = idx & 15;
            *(float4*)&outf[((size_t)b * CCH + o0 + r) * NN + n0 + c4 * 4] =
                *(const float4*)&Of[r][c4 * 4];
        }
    }
}

// ---------------------------------------------------------------------------
// MFMA flash attention: 4 waves x 32 q, Bc=64, kv-split x4.
// Norm-bound fixed softmax max folded into MFMA C-init; l via ones-row MFMA.
// LDS 32KB: K dbuf 16KB + V dbuf 16KB. P tiles live in the dead V[cur^1]
// wave-slice: QK -> exp/pack -> P write -> pb read -> lgkmcnt(0) -> STAGE_V
// overwrites. K prefetch at tile start, V prefetch after P consumed.
// ---------------------------------------------------------------------------
__global__ __launch_bounds__(256, 4)
void attn_kernel(const ushort_t* __restrict__ Qnd,   // bf16 [b][h][n][d]
                 const ushort_t* __restrict__ Knd,   // bf16 [b][h][n][d] *KSCL
                 const ushort_t* __restrict__ Vcn,   // bf16 [b][c][n]
                 const float* __restrict__ kmax2,    // [16] max row-norm^2
                 ushort_t* __restrict__ Op,          // bf16 [4][b][n][c]
                 float* __restrict__ Larr)           // fp32 [4][16][NN]
{
    __shared__ __align__(16) char smem[32768];
    // K2 @0: [2][64][64]sw ; V2 @16384: [2][64][64]sw (P overlays dead V half)

    const int tid = threadIdx.x;
    const int lin0 = blockIdx.x + 18 * blockIdx.y + 288 * blockIdx.z;
    const int w    = (lin0 & 7) * 144 + (lin0 >> 3);   // XCD-chunked remap (1152=8*144)
    const int qt = w % 18;
    const int bh = (w / 18) & 15;
    const int sp = w / 288;
    const int b = bh >> 2, h = bh & 3;
    const int lane = tid & 63, wv = tid >> 6;
    const int lr = lane & 15, lg = lane >> 4;
    const int lrow = lane >> 3, lslot = (lane & 7) ^ lrow;
    const int n0 = qt * 128;
    const size_t ndb = (size_t)(b * HEADS + h) * NN * HD;
    const size_t cnb = ((size_t)b * CCH + h * HD) * NN;

    // staging pointers (pre-swizzled global source, linear LDS dest)
    const char* kgp = (const char*)(Knd + ndb) + (size_t)(sp * 576 + wv * 16 + lrow) * 128 + lslot * 16;
    const char* vgp = (const char*)(Vcn + cnb + sp * 576) + (size_t)(wv * 16 + lrow) * (NN * 2) + lslot * 16;
    char* kls = smem + wv * 2048;
    char* vls = smem + 16384 + wv * 2048;

#define STAGE_K(buf, t) do { \
    const char* kp_ = kgp + (size_t)(t) * 8192; \
    char* kd_ = kls + (buf) * 8192; \
    gload16(kp_,        kd_); \
    gload16(kp_ + 1024, kd_ + 1024); \
} while (0)
#define STAGE_V(buf, t) do { \
    const char* vp_ = vgp + (size_t)(t) * 128; \
    char* vd_ = vls + (buf) * 8192; \
    gload16(vp_,              vd_); \
    gload16(vp_ + 8 * (NN*2), vd_ + 1024); \
} while (0)

    // Q fragments (32 q rows per wave)
    bfrag qb[2][2];
    {
        const ushort_t* qbase = Qnd + ndb + (size_t)(n0 + wv * 32 + lr) * HD;
        qb[0][0] = *(const bfrag*)&qbase[lg * 8];
        qb[0][1] = *(const bfrag*)&qbase[32 + lg * 8];
        qb[1][0] = *(const bfrag*)&qbase[16 * HD + lg * 8];
        qb[1][1] = *(const bfrag*)&qbase[16 * HD + 32 + lg * 8];
    }
    // fixed softmax bound m0 = |q| * max|k'| + margin
    float m0[2];
    {
        const float kmx = sqrtf(kmax2[bh]);
#pragma unroll
        for (int qc = 0; qc < 2; ++qc) {
            const unsigned* u0 = (const unsigned*)&qb[qc][0];
            const unsigned* u1 = (const unsigned*)&qb[qc][1];
            float s = 0.f;
#pragma unroll
            for (int j = 0; j < 4; ++j) {
                float a0 = bflo(u0[j]), a1 = bfhi(u0[j]);
                float b0 = bflo(u1[j]), b1 = bfhi(u1[j]);
                s += a0*a0 + a1*a1 + b0*b0 + b1*b1;
            }
            s += __shfl_xor(s, 16);
            s += __shfl_xor(s, 32);
            m0[qc] = sqrtf(s) * kmx + 0.5f;
        }
    }
    // ones A-fragment (row 0 = 1.0, rows 1..15 = 0) for l accumulation
    bfrag ones_f;
    {
        short ov = (lr == 0) ? (short)0x3F80 : (short)0;
#pragma unroll
        for (int j = 0; j < 8; ++j) ones_f[j] = ov;
    }

    f32x4 o[2][4], o4[2];
#pragma unroll
    for (int qc = 0; qc < 2; ++qc) {
        o4[qc] = (f32x4){0.f, 0.f, 0.f, 0.f};
#pragma unroll
        for (int db = 0; db < 4; ++db) o[qc][db] = (f32x4){0.f, 0.f, 0.f, 0.f};
    }

    const int sw0 = (lg ^ (lr & 7)) << 4;
    const int sw1 = ((4 + lg) ^ (lr & 7)) << 4;

    STAGE_K(0, 0);
    STAGE_V(0, 0);
    __syncthreads();

    for (int t = 0; t < 9; ++t) {
        const int cur = t & 1;
        if (t < 8) STAGE_K(cur ^ 1, t + 1);          // K prefetch: issue early
        const char* Kb = smem + cur * 8192;
        const char* Vb = smem + 16384 + cur * 8192;
        char* Pw = smem + 16384 + (cur ^ 1) * 8192 + wv * 2048;  // dead V slice

        // S^T[64 kk][32 q], C-init = -m0; exp fused per-kb (st dies early)
        uint2 pd[2][4];
#pragma unroll
        for (int kb = 0; kb < 4; ++kb) {
            const char* krow = Kb + (kb * 16 + lr) * 128;
            bfrag ka0 = *(const bfrag*)(krow + sw0);
            bfrag ka1 = *(const bfrag*)(krow + sw1);
            f32x4 z0 = (f32x4){-m0[0], -m0[0], -m0[0], -m0[0]};
            z0 = MFMA(ka0, qb[0][0], z0, 0, 0, 0);
            f32x4 s0 = MFMA(ka1, qb[0][1], z0, 0, 0, 0);
            f32x4 z1 = (f32x4){-m0[1], -m0[1], -m0[1], -m0[1]};
            z1 = MFMA(ka0, qb[1][0], z1, 0, 0, 0);
            f32x4 s1 = MFMA(ka1, qb[1][1], z1, 0, 0, 0);
            pd[0][kb].x = cvtpk(exp2f(s0[0]), exp2f(s0[1]));
            pd[0][kb].y = cvtpk(exp2f(s0[2]), exp2f(s0[3]));
            pd[1][kb].x = cvtpk(exp2f(s1[0]), exp2f(s1[1]));
            pd[1][kb].y = cvtpk(exp2f(s1[2]), exp2f(s1[3]));
        }

        // per-qc: write P into dead V slice (2KB, reused), read back fragments
        bfrag pb[2][2];
#pragma unroll
        for (int qc = 0; qc < 2; ++qc) {
            char* prow = Pw + lr * 128;
#pragma unroll
            for (int kb = 0; kb < 4; ++kb) {
                int slot = (2 * kb + (lg >> 1)) ^ (lr & 7);
                *(uint2*)(prow + slot * 16 + (lg & 1) * 8) = pd[qc][kb];
            }
            pb[qc][0] = *(const bfrag*)(prow + sw0);
            pb[qc][1] = *(const bfrag*)(prow + sw1);
        }
        asm volatile("s_waitcnt lgkmcnt(0)" ::: "memory");   // pb in regs
        if (t < 8) STAGE_V(cur ^ 1, t + 1);          // V prefetch: overwrites P

        // PV: O^T[d][q] += V^T * P^T ; l via ones row
#pragma unroll
        for (int db = 0; db < 4; ++db) {
            const char* vrow = Vb + (db * 16 + lr) * 128;
            bfrag va0 = *(const bfrag*)(vrow + sw0);
            bfrag va1 = *(const bfrag*)(vrow + sw1);
            o[0][db] = MFMA(va0, pb[0][0], o[0][db], 0, 0, 0);
            o[0][db] = MFMA(va1, pb[0][1], o[0][db], 0, 0, 0);
            o[1][db] = MFMA(va0, pb[1][0], o[1][db], 0, 0, 0);
            o[1][db] = MFMA(va1, pb[1][1], o[1][db], 0, 0, 0);
        }
        o4[0] = MFMA(ones_f, pb[0][0], o4[0], 0, 0, 0);
        o4[0] = MFMA(ones_f, pb[0][1], o4[0], 0, 0, 0);
        o4[1] = MFMA(ones_f, pb[1][0], o4[1], 0, 0, 0);
        o4[1] = MFMA(ones_f, pb[1][1], o4[1], 0, 0, 0);

        __syncthreads();   // drains prefetch vmcnt + protects buffers
    }
#undef STAGE_K
#undef STAGE_V

    // epilogue: pack O' bf16, transpose via LDS, coalesced uint4 stores
    if (lg == 0) {
#pragma unroll
        for (int qc = 0; qc < 2; ++qc)
            Larr[(size_t)(sp * 16 + bh) * NN + n0 + wv * 32 + qc * 16 + lr] = o4[qc][0];
    }
    unsigned (*Osb)[36] = (unsigned(*)[36])smem;   // [128][36] u32 (pitch 36)
#pragma unroll
    for (int qc = 0; qc < 2; ++qc) {
        int row = wv * 32 + qc * 16 + lr;
#pragma unroll
        for (int db = 0; db < 4; ++db) {
            Osb[row][db * 8 + lg * 2 + 0] = cvtpk(o[qc][db][0], o[qc][db][1]);
            Osb[row][db * 8 + lg * 2 + 1] = cvtpk(o[qc][db][2], o[qc][db][3]);
        }
    }
    __syncthreads();
    ushort_t* opb = Op + (size_t)sp * BCN + ((size_t)b * NN + n0) * CCH + h * HD;
    for (int idx = tid; idx < 1024; idx += 256) {
        int n = idx >> 3, s4 = idx & 7;
        *(uint4*)&opb[(size_t)n * CCH + s4 * 8] = *(const uint4*)&Osb[n][s4 * 4];
    }
}

// ---------------------------------------------------------------------------
// fuse: sum kv-splits (bf16 O', shared m0) + depthwise 3x3 BN -> bf16 [b][n][c]
// ---------------------------------------------------------------------------
__global__ __launch_bounds__(256)
void fuse_kernel(const ushort_t* __restrict__ Op, const float* __restrict__ Larr,
                 const ushort_t* __restrict__ Qnd,
                 const ushort_t* __restrict__ pw2, const float* __restrict__ pbias,
                 ushort_t* __restrict__ yt)
{
    const int tid = threadIdx.x;
    const int b  = blockIdx.x / 288;
    const int n0 = (blockIdx.x % 288) * 8;
    const int c8 = tid & 31, ns = tid >> 5;
    const int n  = n0 + ns;
    const int h  = c8 >> 3, c0 = c8 * 8;

    const ushort_t* o0p = Op + ((size_t)b * NN + n) * CCH + c0;
    float acc[8] = {0.f, 0.f, 0.f, 0.f, 0.f, 0.f, 0.f, 0.f};
#pragma unroll
    for (int s = 0; s < NSP; ++s) {
        uint4 u = *(const uint4*)&o0p[(size_t)s * BCN];
        acc[0] += bflo(u.x); acc[1] += bfhi(u.x);
        acc[2] += bflo(u.y); acc[3] += bfhi(u.y);
        acc[4] += bflo(u.z); acc[5] += bfhi(u.z);
        acc[6] += bflo(u.w); acc[7] += bfhi(u.w);
    }
    int mi = (b * HEADS + h) * NN + n;
    float ls = 0.f;
#pragma unroll
    for (int s = 0; s < NSP; ++s) ls += Larr[(size_t)s * 16 * NN + mi];
    float rinv = 1.0f / ls;
#pragma unroll
    for (int j = 0; j < 8; ++j) acc[j] *= rinv;

    const int x = n % WW, y = n / WW;
    const ushort_t* qb = Qnd + (size_t)(b * HEADS + h) * NN * HD + (c8 & 7) * 8;
#pragma unroll
    for (int ky = 0; ky < 3; ++ky) {
        int yy = y + ky - 1;
        if (yy < 0 || yy >= HH) continue;
#pragma unroll
        for (int kx = 0; kx < 3; ++kx) {
            int xx = x + kx - 1;
            if (xx < 0 || xx >= WW) continue;
            int np = yy * WW + xx;
            uint4 qv = *(const uint4*)&qb[(size_t)np * HD];
            uint4 w4 = *(const uint4*)&pw2[(ky * 3 + kx) * CCH + c0];
            acc[0] += bflo(qv.x) * bflo(w4.x); acc[1] += bfhi(qv.x) * bfhi(w4.x);
            acc[2] += bflo(qv.y) * bflo(w4.y); acc[3] += bfhi(qv.y) * bfhi(w4.y);
            acc[4] += bflo(qv.z) * bflo(w4.z); acc[5] += bfhi(qv.z) * bfhi(w4.z);
            acc[6] += bflo(qv.w) * bflo(w4.w); acc[7] += bfhi(qv.w) * bfhi(w4.w);
        }
    }
    float4 p0 = *(const float4*)&pbias[c0];
    float4 p1 = *(const float4*)&pbias[c0 + 4];
    acc[0] += p0.x; acc[1] += p0.y; acc[2] += p0.z; acc[3] += p0.w;
    acc[4] += p1.x; acc[5] += p1.y; acc[6] += p1.z; acc[7] += p1.w;
    uint4 u;
    u.x = cvtpk(acc[0], acc[1]); u.y = cvtpk(acc[2], acc[3]);
    u.z = cvtpk(acc[4], acc[5]); u.w = cvtpk(acc[6], acc[7]);
    *(uint4*)&yt[((size_t)b * NN + n) * CCH + c0] = u;
}

// ---------------------------------------------------------------------------
extern "C" void kernel_launch(void* const* d_in, const int* in_sizes, int n_in,
                              void* d_out, int out_size, void* d_ws, size_t ws_size,
                              hipStream_t stream) {
    char* ws = (char*)d_ws;
    ushort_t* qnd  = (ushort_t*)(ws + 0);
    ushort_t* knd  = (ushort_t*)(ws + 4718592);
    ushort_t* vcn  = (ushort_t*)(ws + 9437184);
    ushort_t* Xt   = (ushort_t*)(ws + 14155776);
    ushort_t* Op   = (ushort_t*)(ws + 14155776);   // bf16 [4][BCN], overlays Xt
    ushort_t* yt   = (ushort_t*)(ws + 4718592);    // overlays knd after attn
    float*    Larr = (float*)   (ws + 33030144);   // [4][16][NN] fp32
    ushort_t* W4   = (ushort_t*)(ws + 33619968);
    float*    bias4= (float*)   (ws + 34144256);
    ushort_t* pw2  = (ushort_t*)(ws + 34148352);
    float*    pbias= (float*)   (ws + 34152960);
    float*    kmax2= (float*)   (ws + 34156032);

    PrepWP P;
    P.W[0] = (const float*)d_in[3]; P.W[1] = (const float*)d_in[4];
    P.W[2] = (const float*)d_in[5]; P.W[3] = (const float*)d_in[6];
    P.G[0]  = (const float*)d_in[8];  P.Bb[0] = (const float*)d_in[9];
    P.Mm[0] = (const float*)d_in[10]; P.Vv[0] = (const float*)d_in[11];
    P.G[1]  = (const float*)d_in[12]; P.Bb[1] = (const float*)d_in[13];
    P.Mm[1] = (const float*)d_in[14]; P.Vv[1] = (const float*)d_in[15];
    P.G[2]  = (const float*)d_in[16]; P.Bb[2] = (const float*)d_in[17];
    P.Mm[2] = (const float*)d_in[18]; P.Vv[2] = (const float*)d_in[19];
    P.G[3]  = (const float*)d_in[24]; P.Bb[3] = (const float*)d_in[25];
    P.Mm[3] = (const float*)d_in[26]; P.Vv[3] = (const float*)d_in[27];
    P.pew = (const float*)d_in[7];
    P.peg = (const float*)d_in[20]; P.peb = (const float*)d_in[21];
    P.pem = (const float*)d_in[22]; P.pev = (const float*)d_in[23];
    P.W4 = W4; P.bias4 = bias4; P.pw2 = pw2; P.pbias = pbias; P.kmax2 = kmax2;
    P.q = (const float*)d_in[0]; P.k = (const float*)d_in[1];
    P.v = (const float*)d_in[2]; P.Xt = Xt;

    prep_kernel<<<3585, 256, 0, stream>>>(P);

    conv_gemm<0><<<dim3(36, 4, 12), 256, 0, stream>>>(Xt, W4, bias4, qnd, knd, vcn, nullptr, kmax2);

    attn_kernel<<<dim3(18, 16, NSP), 256, 0, stream>>>(qnd, knd, vcn, kmax2, Op, Larr);

    fuse_kernel<<<1152, 256, 0, stream>>>(Op, Larr, qnd, pw2, pbias, yt);

    conv_gemm<1><<<dim3(36, 4, 4), 256, 0, stream>>>(yt, W4, bias4, nullptr, nullptr, nullptr,
                                                     (float*)d_out, nullptr);
}